// Round 14
// baseline (749.457 us; speedup 1.0000x reference)
//
#include <hip/hip_runtime.h>
#include <hip/hip_bf16.h>

#define D 1024
#define NQ 8192
#define NM 32768
#define TOPK 32
#define NBXT 256  // 128-col tiles per row

typedef __attribute__((ext_vector_type(8))) __bf16 bf16x8;
typedef __attribute__((ext_vector_type(4))) float f32x4;
typedef __attribute__((ext_vector_type(2))) long longx2;

__device__ __forceinline__ void load_lds16(const void* g, void* l) {
  __builtin_amdgcn_global_load_lds(
      (const __attribute__((address_space(1))) void*)g,
      (__attribute__((address_space(3))) void*)l, 16, 0, 0);
}

__device__ __forceinline__ ushort f2bf(float f) {
  unsigned u = __float_as_uint(f);
  unsigned r = (u + 0x7FFFu + ((u >> 16) & 1u)) >> 16;
  return (ushort)r;
}
__device__ __forceinline__ unsigned key16(unsigned u) {
  return u ^ ((u & 0x8000u) ? 0xFFFFu : 0x8000u);
}

#define FP8_SCALE 32.0f
#define INV_ACC (1.0f / 1024.0f)  // (1/FP8_SCALE)^2
#define V8_SCALE 16.0f
#define INV_V8 (1.0f / 16.0f)

// ---------- row L2-normalize f32 -> fp8 e4m3 (x32), k-interleaved layout ----------
__global__ __launch_bounds__(256) void norm_cast8_k(const float* __restrict__ in,
                                                    unsigned* __restrict__ out8) {
  const int row = blockIdx.x;
  const int tid = threadIdx.x;
  const float4 v = ((const float4*)(in + (size_t)row * D))[tid];
  float ss = v.x * v.x + v.y * v.y + v.z * v.z + v.w * v.w;
#pragma unroll
  for (int off = 32; off; off >>= 1) ss += __shfl_xor(ss, off, 64);
  __shared__ float wsum[4];
  const int wid = tid >> 6, lane = tid & 63;
  if (lane == 0) wsum[wid] = ss;
  __syncthreads();
  const float tot = wsum[0] + wsum[1] + wsum[2] + wsum[3];
  const float inv = FP8_SCALE / fmaxf(sqrtf(tot), 1e-12f);
  int r = __builtin_amdgcn_cvt_pk_fp8_f32(v.x * inv, v.y * inv, 0, false);
  r = __builtin_amdgcn_cvt_pk_fp8_f32(v.z * inv, v.w * inv, r, true);
  const int w5 = tid & 31, blk = tid >> 5;
  const int g = w5 >> 1;
  const int h = g >> 2, l4g = g & 3;
  const int G = (h >> 1) * 8 + l4g * 2 + (h & 1);
  out8[(size_t)row * 256 + blk * 32 + G * 2 + (w5 & 1)] = (unsigned)r;
}

// ---------- plain f32 -> fp8 e4m3 cast (V table, x16, linear layout) ----------
__global__ __launch_bounds__(256) void cast_v8_k(const float* __restrict__ in,
                                                 unsigned* __restrict__ out8) {
  const int row = blockIdx.x;
  const int tid = threadIdx.x;
  const float4 v = ((const float4*)(in + (size_t)row * D))[tid];
  int r = __builtin_amdgcn_cvt_pk_fp8_f32(v.x * V8_SCALE, v.y * V8_SCALE, 0, false);
  r = __builtin_amdgcn_cvt_pk_fp8_f32(v.z * V8_SCALE, v.w * V8_SCALE, r, true);
  out8[(size_t)row * 256 + tid] = (unsigned)r;
}

// ---------- 128x128 fp8 GEMM, BK=128, T3-minimum double-buffer ----------
// Per K-tile: issue STAGE(t+1 -> buf^1) BEFORE computing buf(t); ONE
// __syncthreads per tile (its vmcnt(0) drains loads that had the whole
// compute phase to land). buf^1 free: last read in tile t-1, drained at
// the t-1 barrier. LDS 64KB -> 2 blocks/CU; hiding is intra-block.
__global__ __launch_bounds__(256, 2) void gemm128(const uchar* __restrict__ A8,
                                                  const uchar* __restrict__ B8,
                                                  ushort* __restrict__ C,
                                                  ushort* __restrict__ TM,
                                                  int nby, int srows) {
  __shared__ alignas(16) ushort lds[32768];  // 64KB: A[2][16K] | B[2][16K]; C-stage aliases
  __shared__ float wmax[2][128];
  uchar* const AS = (uchar*)lds;
  uchar* const BS = (uchar*)lds + 32768;
  const int tid = threadIdx.x;
  const int lane = tid & 63, wid = tid >> 6;
  const int l15 = lane & 15, l4 = lane >> 4;

  // T1: bijective XCD swizzle
  const int nwg = (int)gridDim.x;
  const int q = nwg >> 3, r = nwg & 7;
  const int xcd = (int)blockIdx.x & 7, pos = (int)blockIdx.x >> 3;
  const int wg = (xcd < r ? xcd * (q + 1) : r * (q + 1) + (xcd - r) * q) + pos;
  const int bx = wg / nby, by = wg % nby;

  const int wr = wid >> 1, wc = wid & 1;  // 2x2 waves, each 64x64 of C

  f32x4 acc[4][4];
#pragma unroll
  for (int m = 0; m < 4; m++)
#pragma unroll
    for (int n = 0; n < 4; n++) acc[m][n] = f32x4{0.f, 0.f, 0.f, 0.f};

  // staging source (pre-swizzled global, linear LDS dest) — as R13
  const int srow = tid >> 3;
  const int cc = ((tid & 7) ^ ((tid >> 3) & 7)) << 4;
  const uchar* gA = A8 + ((size_t)by * 128 + srow) * 1024 + cc;
  const uchar* gB = B8 + ((size_t)bx * 128 + srow) * 1024 + cc;

#define STAGE8(tt, b)                                                     \
  do {                                                                    \
    const int ko_ = (tt) * 128;                                           \
    uchar* const dA_ = AS + (b) * 16384 + wid * 1024;                     \
    uchar* const dB_ = BS + (b) * 16384 + wid * 1024;                     \
    _Pragma("unroll") for (int l_ = 0; l_ < 4; ++l_) {                    \
      load_lds16(gA + (size_t)l_ * 32 * 1024 + ko_, dA_ + l_ * 4096);     \
      load_lds16(gB + (size_t)l_ * 32 * 1024 + ko_, dB_ + l_ * 4096);     \
    }                                                                     \
  } while (0)

  // frag reads: logical chunk hp*4+l4 stored at ^(l15&7); b128 covers 2 k-steps
  const int ob0 = (((0 + l4) ^ (l15 & 7)) << 4);
  const int ob1 = (((4 + l4) ^ (l15 & 7)) << 4);

  STAGE8(0, 0);
  __syncthreads();

#pragma unroll 1
  for (int kt = 0; kt < 8; ++kt) {
    const int b = kt & 1;
    if (kt < 7) STAGE8(kt + 1, b ^ 1);
    const uchar* const abase = AS + b * 16384 + (wr * 64 + l15) * 128;
    const uchar* const bbase = BS + b * 16384 + (wc * 64 + l15) * 128;
#pragma unroll
    for (int hp = 0; hp < 2; ++hp) {
      const int ob = hp ? ob1 : ob0;
      longx2 af[4], bfv[4];
#pragma unroll
      for (int m = 0; m < 4; ++m) af[m] = *(const longx2*)(abase + m * 2048 + ob);
#pragma unroll
      for (int n = 0; n < 4; ++n) bfv[n] = *(const longx2*)(bbase + n * 2048 + ob);
#pragma unroll
      for (int m = 0; m < 4; ++m)
#pragma unroll
        for (int n = 0; n < 4; ++n) {
          acc[m][n] = __builtin_amdgcn_mfma_f32_16x16x32_fp8_fp8(af[m].x, bfv[n].x, acc[m][n], 0, 0, 0);
          acc[m][n] = __builtin_amdgcn_mfma_f32_16x16x32_fp8_fp8(af[m].y, bfv[n].y, acc[m][n], 0, 0, 0);
        }
    }
    __syncthreads();
  }
#undef STAGE8

  // epilogue 1: per-row max over this block's 128 cols (atomic-free); scale acc
#pragma unroll
  for (int m = 0; m < 4; ++m)
#pragma unroll
    for (int j = 0; j < 4; ++j) {
      float fm = fmaxf(fmaxf(acc[m][0][j], acc[m][1][j]), fmaxf(acc[m][2][j], acc[m][3][j]));
#pragma unroll
      for (int off = 1; off < 16; off <<= 1) fm = fmaxf(fm, __shfl_xor(fm, off, 64));
      if (l15 == 0) wmax[wc][wr * 64 + l4 * 4 + m * 16 + j] = fm;
    }
  __syncthreads();
  if (tid < 128) {
    const float fm = fmaxf(wmax[0][tid], wmax[1][tid]) * INV_ACC;
    TM[(size_t)bx * srows + by * 128 + tid] = (ushort)key16((unsigned)f2bf(fm));
  }

  // epilogue 2: stage C-tile to LDS (chunk-XOR swizzle), stream out coalesced.
#pragma unroll
  for (int m = 0; m < 4; ++m)
#pragma unroll
    for (int n = 0; n < 4; ++n) {
      const int col = wc * 64 + n * 16 + l15;
      const int c8 = col >> 3, c7 = col & 7;
#pragma unroll
      for (int j = 0; j < 4; ++j) {
        const int row = wr * 64 + m * 16 + l4 * 4 + j;
        lds[row * 128 + ((c8 ^ (row & 7)) << 3) + c7] = f2bf(acc[m][n][j] * INV_ACC);
      }
    }
  __syncthreads();
  const int orow = tid >> 4, seg = tid & 15;
#pragma unroll
  for (int p = 0; p < 8; ++p) {
    const int row = p * 16 + orow;
    const bf16x8 v = *(const bf16x8*)&lds[row * 128 + ((seg ^ (row & 7)) << 3)];
    *(bf16x8*)&C[((size_t)by * 128 + row) * NM + bx * 128 + seg * 8] = v;
  }
}

// ---------- top-32 with 128-col tile-max prefilter (unchanged) ----------
#define CAP2 1024
__global__ __launch_bounds__(512) void topk_k(const ushort* __restrict__ scores,
                                              const ushort* __restrict__ tmax,
                                              int srows, int row_base,
                                              const float* __restrict__ temp,
                                              float* __restrict__ attn,
                                              int* __restrict__ idx_out) {
  const int lrow = blockIdx.x;
  const int grow = row_base + lrow;
  const int tid = threadIdx.x;
  const int lane = tid & 63, wid = tid >> 6;
  __shared__ unsigned tlb_s, M_s;
  __shared__ int nqt_s, cnt_s;
  __shared__ ushort qt[NBXT];
  __shared__ unsigned ckey[CAP2];
  __shared__ unsigned cand64[64];
  __shared__ unsigned okey[TOPK];
  __shared__ int oidx[TOPK];

  if (tid == 0) cnt_s = 0;

  if (tid < 64) {
    const unsigned k0 = tmax[(size_t)lane * srows + lrow];
    const unsigned k1 = tmax[(size_t)(lane + 64) * srows + lrow];
    const unsigned k2 = tmax[(size_t)(lane + 128) * srows + lrow];
    const unsigned k3 = tmax[(size_t)(lane + 192) * srows + lrow];
    unsigned mx = max(max(k0, k1), max(k2, k3));
#pragma unroll
    for (int off = 32; off; off >>= 1) mx = max(mx, __shfl_xor(mx, off, 64));
    unsigned lo = 0, hi = mx;
    while (lo < hi) {
      const unsigned mid = (lo + hi + 1) >> 1;
      int c = (int)(k0 >= mid) + (int)(k1 >= mid) + (int)(k2 >= mid) + (int)(k3 >= mid);
#pragma unroll
      for (int off = 32; off; off >>= 1) c += __shfl_xor(c, off, 64);
      if (c >= TOPK) lo = mid; else hi = mid - 1;
    }
    int base = 0;
    {
      const bool p = k0 >= lo;
      const unsigned long long bm = __ballot(p);
      if (p) qt[base + __popcll(bm & ((1ull << lane) - 1ull))] = (ushort)lane;
      base += __popcll(bm);
    }
    {
      const bool p = k1 >= lo;
      const unsigned long long bm = __ballot(p);
      if (p) qt[base + __popcll(bm & ((1ull << lane) - 1ull))] = (ushort)(lane + 64);
      base += __popcll(bm);
    }
    {
      const bool p = k2 >= lo;
      const unsigned long long bm = __ballot(p);
      if (p) qt[base + __popcll(bm & ((1ull << lane) - 1ull))] = (ushort)(lane + 128);
      base += __popcll(bm);
    }
    {
      const bool p = k3 >= lo;
      const unsigned long long bm = __ballot(p);
      if (p) qt[base + __popcll(bm & ((1ull << lane) - 1ull))] = (ushort)(lane + 192);
      base += __popcll(bm);
    }
    if (lane == 0) { nqt_s = base; tlb_s = lo; M_s = mx; }
  }
  __syncthreads();
  const unsigned M = M_s;
  const int nqt = nqt_s;
  unsigned t0 = tlb_s;
  unsigned tlo = t0, thi = M;

  const unsigned* rowu = (const unsigned*)(scores + (size_t)lrow * NM);
  int cnt = 0;
  for (int att = 0; att < 18; ++att) {
    for (int i = wid; i < nqt; i += 8) {
      const int tb = qt[i];
      const unsigned u = rowu[tb * 64 + lane];
      const unsigned m = (u >> 15) & 0x00010001u;
      const unsigned kk = u ^ (m * 0x7FFFu + 0x80008000u);
      const unsigned klo = kk & 0xFFFFu, khi = kk >> 16;
      const int bidx = tb * 128 + lane * 2;
      if (klo >= t0) { const int qq = atomicAdd(&cnt_s, 1); if (qq < CAP2) ckey[qq] = (klo << 16) | (unsigned)(32767 - bidx); }
      if (khi >= t0) { const int qq = atomicAdd(&cnt_s, 1); if (qq < CAP2) ckey[qq] = (khi << 16) | (unsigned)(32767 - (bidx + 1)); }
    }
    __syncthreads();
    cnt = cnt_s;
    __syncthreads();
    if ((cnt >= TOPK && cnt <= CAP2) || att == 17) break;
    if (cnt > CAP2) { tlo = t0; t0 = t0 + ((thi - t0 + 1) >> 1); }
    else { thi = t0; t0 = tlo + ((t0 - tlo) >> 1); }
    if (tid == 0) cnt_s = 0;
    __syncthreads();
  }
  const int n = min(cnt, CAP2);

  if (tid < 64) {
    unsigned lo = t0, hi = M;
    while (lo < hi) {
      const unsigned mid = (lo + hi + 1) >> 1;
      int c = 0;
      for (int i = lane; i < n; i += 64) c += (int)((ckey[i] >> 16) >= mid);
#pragma unroll
      for (int off = 32; off; off >>= 1) c += __shfl_xor(c, off, 64);
      if (c >= TOPK) lo = mid; else hi = mid - 1;
    }
    const unsigned t32 = lo;
    int c32 = 0;
    for (int i = lane; i < n; i += 64) c32 += (int)((ckey[i] >> 16) >= t32);
#pragma unroll
    for (int off = 32; off; off >>= 1) c32 += __shfl_xor(c32, off, 64);

    if (c32 <= 64) {
      cand64[lane] = 0;
      int base = 0;
      for (int r0 = 0; r0 < n; r0 += 64) {
        const int i = r0 + lane;
        const unsigned k = (i < n) ? ckey[i] : 0u;
        const bool p = (k >> 16) >= t32;
        const unsigned long long bm = __ballot(p);
        if (p) {
          const int ps = base + __popcll(bm & ((1ull << lane) - 1ull));
          if (ps < 64) cand64[ps] = k;
        }
        base += __popcll(bm);
      }
      unsigned v = cand64[lane];
#pragma unroll
      for (int k2 = 2; k2 <= 64; k2 <<= 1) {
#pragma unroll
        for (int j = k2 >> 1; j > 0; j >>= 1) {
          const unsigned o = __shfl_xor(v, j, 64);
          const bool lower = (lane & j) == 0;
          const bool descB = (lane & k2) == 0;
          const unsigned mxv = v > o ? v : o;
          const unsigned mnv = v > o ? o : v;
          v = (lower == descB) ? mxv : mnv;
        }
      }
      if (lane < TOPK) {
        okey[lane] = v >> 16;
        oidx[lane] = 32767 - (int)(v & 0x7FFFu);
      }
    } else {
      for (int k = 0; k < TOPK; ++k) {
        unsigned bk = 0;
        for (int j = lane; j < n; j += 64) bk = max(bk, ckey[j]);
#pragma unroll
        for (int off = 32; off; off >>= 1) bk = max(bk, __shfl_xor(bk, off, 64));
        if (lane == 0) {
          okey[k] = bk >> 16;
          oidx[k] = 32767 - (int)(bk & 0x7FFFu);
        }
        for (int j = lane; j < n; j += 64)
          if (ckey[j] == bk) ckey[j] = 0;
      }
    }
  }
  __syncthreads();

  if (tid < TOPK) {
    const float T = fabsf(temp[0]);
    const unsigned k0 = okey[tid];
    const unsigned u0 = (k0 & 0x8000u) ? (k0 ^ 0x8000u) : (k0 ^ 0xFFFFu);
    const unsigned km = okey[0];
    const unsigned um = (km & 0x8000u) ? (km ^ 0x8000u) : (km ^ 0xFFFFu);
    const float s = __uint_as_float(u0 << 16) * T;
    const float mx = __uint_as_float(um << 16) * T;
    const float e = __expf(s - mx);
    float sum = e;
#pragma unroll
    for (int off = 16; off; off >>= 1) sum += __shfl_xor(sum, off, 32);
    attn[(size_t)grow * TOPK + tid] = e / sum;
    idx_out[(size_t)grow * TOPK + tid] = oidx[tid];
  }
}

// ---------- fp8-V gather + residual + LayerNorm, 2 rows/block ----------
__global__ __launch_bounds__(256) void gather_ln_f8(const uchar* __restrict__ V8,
                                                    const float* __restrict__ Q,
                                                    const float* __restrict__ gamma,
                                                    const float* __restrict__ beta,
                                                    const float* __restrict__ attn,
                                                    const int* __restrict__ idx,
                                                    float* __restrict__ out) {
  const int tid = threadIdx.x;
  const int rh = tid >> 7;
  const int t7 = tid & 127;
  const int row = blockIdx.x * 2 + rh;
  __shared__ float a_s[2][TOPK];
  __shared__ int i_s[2][TOPK];
  __shared__ float redS[2][2], redQ[2][2];
  if (t7 < TOPK) {
    a_s[rh][t7] = attn[(size_t)row * TOPK + t7];
    i_s[rh][t7] = idx[(size_t)row * TOPK + t7];
  }
  __syncthreads();

  const int e0 = t7 * 8;  // 8 fp8 elements (8 bytes) per thread
  float acc[8];
#pragma unroll
  for (int u = 0; u < 8; ++u) acc[u] = 0.f;
#pragma unroll
  for (int kb = 0; kb < TOPK; kb += 8) {
    uint2 v[8];
#pragma unroll
    for (int u = 0; u < 8; ++u)
      v[u] = *(const uint2*)&V8[(size_t)i_s[rh][kb + u] * D + e0];
#pragma unroll
    for (int u = 0; u < 8; ++u) {
      const float a = a_s[rh][kb + u];
      acc[0] = fmaf(a, __builtin_amdgcn_cvt_f32_fp8((int)v[u].x, 0), acc[0]);
      acc[1] = fmaf(a, __builtin_amdgcn_cvt_f32_fp8((int)v[u].x, 1), acc[1]);
      acc[2] = fmaf(a, __builtin_amdgcn_cvt_f32_fp8((int)v[u].x, 2), acc[2]);
      acc[3] = fmaf(a, __builtin_amdgcn_cvt_f32_fp8((int)v[u].x, 3), acc[3]);
      acc[4] = fmaf(a, __builtin_amdgcn_cvt_f32_fp8((int)v[u].y, 0), acc[4]);
      acc[5] = fmaf(a, __builtin_amdgcn_cvt_f32_fp8((int)v[u].y, 1), acc[5]);
      acc[6] = fmaf(a, __builtin_amdgcn_cvt_f32_fp8((int)v[u].y, 2), acc[6]);
      acc[7] = fmaf(a, __builtin_amdgcn_cvt_f32_fp8((int)v[u].y, 3), acc[7]);
    }
  }

  const float4 q0 = *(const float4*)&Q[(size_t)row * D + e0];
  const float4 q1 = *(const float4*)&Q[(size_t)row * D + e0 + 4];
  float x[8] = {acc[0] * INV_V8 + q0.x, acc[1] * INV_V8 + q0.y,
                acc[2] * INV_V8 + q0.z, acc[3] * INV_V8 + q0.w,
                acc[4] * INV_V8 + q1.x, acc[5] * INV_V8 + q1.y,
                acc[6] * INV_V8 + q1.z, acc[7] * INV_V8 + q1.w};
  float s = 0.f, ss = 0.f;
#pragma unroll
  for (int c = 0; c < 8; ++c) { s += x[c]; ss += x[c] * x[c]; }
#pragma unroll
  for (int off = 32; off; off >>= 1) {
    s += __shfl_xor(s, off, 64);
    ss += __shfl_xor(ss, off, 64);
  }
  const int w2 = (t7 >> 6);
  if ((tid & 63) == 0) { redS[rh][w2] = s; redQ[rh][w2] = ss; }
  __syncthreads();
  const float S = redS[rh][0] + redS[rh][1];
  const float SS = redQ[rh][0] + redQ[rh][1];
  const float mu = S * (1.0f / D);
  const float var = SS * (1.0f / D) - mu * mu;
  const float rstd = rsqrtf(var + 1e-5f);
  const float4 g0 = *(const float4*)&gamma[e0];
  const float4 g1 = *(const float4*)&gamma[e0 + 4];
  const float4 b0 = *(const float4*)&beta[e0];
  const float4 b1 = *(const float4*)&beta[e0 + 4];
  const float g[8] = {g0.x, g0.y, g0.z, g0.w, g1.x, g1.y, g1.z, g1.w};
  const float b[8] = {b0.x, b0.y, b0.z, b0.w, b1.x, b1.y, b1.z, b1.w};
  float4 o0, o1;
  o0.x = (x[0] - mu) * rstd * g[0] + b[0];
  o0.y = (x[1] - mu) * rstd * g[1] + b[1];
  o0.z = (x[2] - mu) * rstd * g[2] + b[2];
  o0.w = (x[3] - mu) * rstd * g[3] + b[3];
  o1.x = (x[4] - mu) * rstd * g[4] + b[4];
  o1.y = (x[5] - mu) * rstd * g[5] + b[5];
  o1.z = (x[6] - mu) * rstd * g[6] + b[6];
  o1.w = (x[7] - mu) * rstd * g[7] + b[7];
  *(float4*)&out[(size_t)row * D + e0] = o0;
  *(float4*)&out[(size_t)row * D + e0 + 4] = o1;
}

// ---------- fp32 fallback gather ----------
__global__ __launch_bounds__(256) void gather_ln_k(const float* __restrict__ V,
                                                   const float* __restrict__ Q,
                                                   const float* __restrict__ gamma,
                                                   const float* __restrict__ beta,
                                                   const float* __restrict__ attn,
                                                   const int* __restrict__ idx,
                                                   float* __restrict__ out) {
  const int row = blockIdx.x, tid = threadIdx.x;
  __shared__ float a_s[TOPK];
  __shared__ int i_s[TOPK];
  __shared__ float redS[4], redQ[4];
  if (tid < TOPK) {
    a_s[tid] = attn[(size_t)row * TOPK + tid];
    i_s[tid] = idx[(size_t)row * TOPK + tid];
  }
  __syncthreads();
  float4 acc = {0.f, 0.f, 0.f, 0.f};
#pragma unroll
  for (int kb = 0; kb < TOPK; kb += 8) {
    float4 v[8];
#pragma unroll
    for (int u = 0; u < 8; ++u)
      v[u] = ((const float4*)(V + (size_t)i_s[kb + u] * D))[tid];
#pragma unroll
    for (int u = 0; u < 8; ++u) {
      const float a = a_s[kb + u];
      acc.x = fmaf(a, v[u].x, acc.x);
      acc.y = fmaf(a, v[u].y, acc.y);
      acc.z = fmaf(a, v[u].z, acc.z);
      acc.w = fmaf(a, v[u].w, acc.w);
    }
  }
  const float4 q = ((const float4*)(Q + (size_t)row * D))[tid];
  float4 x = {acc.x + q.x, acc.y + q.y, acc.z + q.z, acc.w + q.w};
  float s = x.x + x.y + x.z + x.w;
  float ss = x.x * x.x + x.y * x.y + x.z * x.z + x.w * x.w;
#pragma unroll
  for (int off = 32; off; off >>= 1) {
    s += __shfl_xor(s, off, 64);
    ss += __shfl_xor(ss, off, 64);
  }
  const int wid = tid >> 6, lane = tid & 63;
  if (lane == 0) { redS[wid] = s; redQ[wid] = ss; }
  __syncthreads();
  const float S = redS[0] + redS[1] + redS[2] + redS[3];
  const float SS = redQ[0] + redQ[1] + redQ[2] + redQ[3];
  const float mu = S * (1.0f / D);
  const float var = SS * (1.0f / D) - mu * mu;
  const float rstd = rsqrtf(var + 1e-5f);
  const float4 g = ((const float4*)gamma)[tid];
  const float4 b = ((const float4*)beta)[tid];
  float4 o;
  o.x = (x.x - mu) * rstd * g.x + b.x;
  o.y = (x.y - mu) * rstd * g.y + b.y;
  o.z = (x.z - mu) * rstd * g.z + b.z;
  o.w = (x.w - mu) * rstd * g.w + b.w;
  ((float4*)(out + (size_t)row * D))[tid] = o;
}

extern "C" void kernel_launch(void* const* d_in, const int* in_sizes, int n_in,
                              void* d_out, int out_size, void* d_ws, size_t ws_size,
                              hipStream_t stream) {
  const float* Q = (const float*)d_in[0];
  const float* K = (const float*)d_in[1];
  const float* V = (const float*)d_in[2];
  const float* T = (const float*)d_in[3];
  const float* G = (const float*)d_in[4];
  const float* Bt = (const float*)d_in[5];
  float* out = (float*)d_out;
  float* attn = out + (size_t)NQ * D;

  char* ws = (char*)d_ws;
  const size_t off_q8 = 0;
  const size_t off_k8 = off_q8 + (size_t)NQ * D;                      // 8 MB
  const size_t off_idx = off_k8 + (size_t)NM * D;                     // +32 MB
  const size_t off_tm = off_idx + (size_t)NQ * TOPK * sizeof(int);    // +1 MB
  const size_t off_v8 = off_tm + (size_t)NBXT * 2048 * 2;             // +1 MB
  const size_t v8_bytes = (size_t)NM * D;                             // 32 MB

  const bool use_v8 = ws_size >= off_v8 + v8_bytes + (size_t)256 * NM * 2;
  const size_t off_sc = use_v8 ? off_v8 + v8_bytes : off_v8;

  unsigned* q8 = (unsigned*)(ws + off_q8);
  unsigned* k8 = (unsigned*)(ws + off_k8);
  int* idx = (int*)(ws + off_idx);
  ushort* tm = (ushort*)(ws + off_tm);
  unsigned* v8 = (unsigned*)(ws + off_v8);
  ushort* scores = (ushort*)(ws + off_sc);

  const size_t avail = ws_size > off_sc ? ws_size - off_sc : 0;
  int slice = 2048;
  while (slice > 256 && (size_t)slice * NM * 2ull > avail) slice >>= 1;

  norm_cast8_k<<<NQ, 256, 0, stream>>>(Q, q8);
  norm_cast8_k<<<NM, 256, 0, stream>>>(K, k8);
  if (use_v8) cast_v8_k<<<NM, 256, 0, stream>>>(V, v8);

  const int nbx = NM / 128;
  for (int s0 = 0; s0 < NQ; s0 += slice) {
    const int nby = slice / 128;
    gemm128<<<nbx * nby, 256, 0, stream>>>((const uchar*)q8 + (size_t)s0 * D,
                                           (const uchar*)k8, scores, tm, nby, slice);
    topk_k<<<slice, 512, 0, stream>>>(scores, tm, slice, s0, T, attn, idx);
  }
  if (use_v8)
    gather_ln_f8<<<NQ / 2, 256, 0, stream>>>((const uchar*)v8, Q, G, Bt, attn, idx, out);
  else
    gather_ln_k<<<NQ, 256, 0, stream>>>(V, Q, G, Bt, attn, idx, out);
}

// Round 15
// 638.372 us; speedup vs baseline: 1.1740x; 1.1740x over previous
//
#include <hip/hip_runtime.h>
#include <hip/hip_bf16.h>

#define D 1024
#define NQ 8192
#define NM 32768
#define TOPK 32
#define NBXT 256  // 128-col tiles per row

typedef __attribute__((ext_vector_type(8))) __bf16 bf16x8;
typedef __attribute__((ext_vector_type(4))) float f32x4;
typedef __attribute__((ext_vector_type(2))) long longx2;

__device__ __forceinline__ void load_lds16(const void* g, void* l) {
  __builtin_amdgcn_global_load_lds(
      (const __attribute__((address_space(1))) void*)g,
      (__attribute__((address_space(3))) void*)l, 16, 0, 0);
}

__device__ __forceinline__ ushort f2bf(float f) {
  unsigned u = __float_as_uint(f);
  unsigned r = (u + 0x7FFFu + ((u >> 16) & 1u)) >> 16;
  return (ushort)r;
}
__device__ __forceinline__ unsigned key16(unsigned u) {
  return u ^ ((u & 0x8000u) ? 0xFFFFu : 0x8000u);
}

#define FP8_SCALE 32.0f
#define INV_ACC (1.0f / 1024.0f)  // (1/FP8_SCALE)^2
#define V8_SCALE 16.0f
#define INV_V8 (1.0f / 16.0f)

// ---------- row L2-normalize f32 -> fp8 e4m3 (x32), k-interleaved layout ----------
// (unchanged from R13: within each 128-elem k-block, granule (h,l4) at
// G=(h>>1)*8+l4*2+(h&1); a 64-elem k-tile's lane-granules are contiguous 16B
// at chunk l4 within its 64B half — the BK=64 read unit.)
__global__ __launch_bounds__(256) void norm_cast8_k(const float* __restrict__ in,
                                                    unsigned* __restrict__ out8) {
  const int row = blockIdx.x;
  const int tid = threadIdx.x;
  const float4 v = ((const float4*)(in + (size_t)row * D))[tid];
  float ss = v.x * v.x + v.y * v.y + v.z * v.z + v.w * v.w;
#pragma unroll
  for (int off = 32; off; off >>= 1) ss += __shfl_xor(ss, off, 64);
  __shared__ float wsum[4];
  const int wid = tid >> 6, lane = tid & 63;
  if (lane == 0) wsum[wid] = ss;
  __syncthreads();
  const float tot = wsum[0] + wsum[1] + wsum[2] + wsum[3];
  const float inv = FP8_SCALE / fmaxf(sqrtf(tot), 1e-12f);
  int r = __builtin_amdgcn_cvt_pk_fp8_f32(v.x * inv, v.y * inv, 0, false);
  r = __builtin_amdgcn_cvt_pk_fp8_f32(v.z * inv, v.w * inv, r, true);
  const int w5 = tid & 31, blk = tid >> 5;
  const int g = w5 >> 1;
  const int h = g >> 2, l4g = g & 3;
  const int G = (h >> 1) * 8 + l4g * 2 + (h & 1);
  out8[(size_t)row * 256 + blk * 32 + G * 2 + (w5 & 1)] = (unsigned)r;
}

// ---------- plain f32 -> fp8 e4m3 cast (V table, x16, linear layout) ----------
__global__ __launch_bounds__(256) void cast_v8_k(const float* __restrict__ in,
                                                 unsigned* __restrict__ out8) {
  const int row = blockIdx.x;
  const int tid = threadIdx.x;
  const float4 v = ((const float4*)(in + (size_t)row * D))[tid];
  int r = __builtin_amdgcn_cvt_pk_fp8_f32(v.x * V8_SCALE, v.y * V8_SCALE, 0, false);
  r = __builtin_amdgcn_cvt_pk_fp8_f32(v.z * V8_SCALE, v.w * V8_SCALE, r, true);
  out8[(size_t)row * 256 + tid] = (unsigned)r;
}

// ---------- 128x128 fp8 GEMM, BK=64 double-buffer, 4 blocks/CU ----------
// R14's dbuf sync structure (stage t+1 -> buf^1 before computing buf t, ONE
// __syncthreads per tile) at HALF the LDS (32KB) -> occupancy restored to
// 4 blocks/CU. LDS layout: row-pairs per 128B line ((r>>1)*128+(r&1)*64),
// chunk XOR (r>>1)&3 on both staging source and frag reads.
__global__ __launch_bounds__(256, 4) void gemm128(const uchar* __restrict__ A8,
                                                  const uchar* __restrict__ B8,
                                                  ushort* __restrict__ C,
                                                  ushort* __restrict__ TM,
                                                  int nby, int srows) {
  __shared__ alignas(16) ushort lds[16384];  // 32KB: A[2][8K] | B[2][8K]; C-stage aliases
  __shared__ float wmax[2][128];
  uchar* const AS = (uchar*)lds;
  uchar* const BS = (uchar*)lds + 16384;
  const int tid = threadIdx.x;
  const int lane = tid & 63, wid = tid >> 6;
  const int l15 = lane & 15, l4 = lane >> 4;

  // T1: bijective XCD swizzle
  const int nwg = (int)gridDim.x;
  const int q = nwg >> 3, r = nwg & 7;
  const int xcd = (int)blockIdx.x & 7, pos = (int)blockIdx.x >> 3;
  const int wg = (xcd < r ? xcd * (q + 1) : r * (q + 1) + (xcd - r) * q) + pos;
  const int bx = wg / nby, by = wg % nby;

  const int wr = wid >> 1, wc = wid & 1;  // 2x2 waves, each 64x64 of C

  f32x4 acc[4][4];
#pragma unroll
  for (int m = 0; m < 4; m++)
#pragma unroll
    for (int n = 0; n < 4; n++) acc[m][n] = f32x4{0.f, 0.f, 0.f, 0.f};

  // staging: 512 chunks(16B)/operand/tile; thread t, load l in {0,1}:
  // dest ci = l*256+t -> line L=ci>>3, slot s=t&7; holds row l*64+(t>>3)*2+((t>>2)&1),
  // logical chunk (t&3)^((t>>3)&3)  (pre-swizzled source, linear LDS dest).
  const int r0 = (tid >> 3) * 2 + ((tid >> 2) & 1);
  const int cSrc = ((tid & 3) ^ ((tid >> 3) & 3)) << 4;
  const uchar* gA = A8 + ((size_t)by * 128 + r0) * 1024 + cSrc;
  const uchar* gB = B8 + ((size_t)bx * 128 + r0) * 1024 + cSrc;

#define STAGE8(tt, b)                                                        \
  do {                                                                       \
    const int ko_ = (tt) * 64;                                               \
    load_lds16(gA + ko_, AS + (b)*8192 + wid * 1024);                        \
    load_lds16(gA + 64 * 1024 + ko_, AS + (b)*8192 + 4096 + wid * 1024);     \
    load_lds16(gB + ko_, BS + (b)*8192 + wid * 1024);                        \
    load_lds16(gB + 64 * 1024 + ko_, BS + (b)*8192 + 4096 + wid * 1024);     \
  } while (0)

  // frag reads: row rr = {wr|wc}*64 + m*16 + l15 -> addr (rr>>1)*128 + (rr&1)*64
  // + (l4 ^ ((l15>>1)&3))*16; one b128 = both k-steps (h=0 lo, h=1 hi).
  const int obx = (l4 ^ ((l15 >> 1) & 3)) << 4;
  const int arow = (wr * 32 + (l15 >> 1)) * 128 + (l15 & 1) * 64 + obx;
  const int brow = (wc * 32 + (l15 >> 1)) * 128 + (l15 & 1) * 64 + obx;

  STAGE8(0, 0);
  __syncthreads();

#pragma unroll 1
  for (int kt = 0; kt < 16; ++kt) {
    const int b = kt & 1;
    if (kt < 15) STAGE8(kt + 1, b ^ 1);
    const uchar* const abase = AS + b * 8192 + arow;
    const uchar* const bbase = BS + b * 8192 + brow;
    longx2 af[4], bfv[4];
#pragma unroll
    for (int m = 0; m < 4; ++m) af[m] = *(const longx2*)(abase + m * 1024);
#pragma unroll
    for (int n = 0; n < 4; ++n) bfv[n] = *(const longx2*)(bbase + n * 1024);
#pragma unroll
    for (int m = 0; m < 4; ++m)
#pragma unroll
      for (int n = 0; n < 4; ++n) {
        acc[m][n] = __builtin_amdgcn_mfma_f32_16x16x32_fp8_fp8(af[m].x, bfv[n].x, acc[m][n], 0, 0, 0);
        acc[m][n] = __builtin_amdgcn_mfma_f32_16x16x32_fp8_fp8(af[m].y, bfv[n].y, acc[m][n], 0, 0, 0);
      }
    __syncthreads();
  }
#undef STAGE8

  // epilogue 1: per-row max over this block's 128 cols (atomic-free); scale acc
#pragma unroll
  for (int m = 0; m < 4; ++m)
#pragma unroll
    for (int j = 0; j < 4; ++j) {
      float fm = fmaxf(fmaxf(acc[m][0][j], acc[m][1][j]), fmaxf(acc[m][2][j], acc[m][3][j]));
#pragma unroll
      for (int off = 1; off < 16; off <<= 1) fm = fmaxf(fm, __shfl_xor(fm, off, 64));
      if (l15 == 0) wmax[wc][wr * 64 + l4 * 4 + m * 16 + j] = fm;
    }
  __syncthreads();
  if (tid < 128) {
    const float fm = fmaxf(wmax[0][tid], wmax[1][tid]) * INV_ACC;
    TM[(size_t)bx * srows + by * 128 + tid] = (ushort)key16((unsigned)f2bf(fm));
  }

  // epilogue 2: stage C-tile to LDS (chunk-XOR swizzle), stream out coalesced.
#pragma unroll
  for (int m = 0; m < 4; ++m)
#pragma unroll
    for (int n = 0; n < 4; ++n) {
      const int col = wc * 64 + n * 16 + l15;
      const int c8 = col >> 3, c7 = col & 7;
#pragma unroll
      for (int j = 0; j < 4; ++j) {
        const int row = wr * 64 + m * 16 + l4 * 4 + j;
        lds[row * 128 + ((c8 ^ (row & 7)) << 3) + c7] = f2bf(acc[m][n][j] * INV_ACC);
      }
    }
  __syncthreads();
  const int orow = tid >> 4, seg = tid & 15;
#pragma unroll
  for (int p = 0; p < 8; ++p) {
    const int row = p * 16 + orow;
    const bf16x8 v = *(const bf16x8*)&lds[row * 128 + ((seg ^ (row & 7)) << 3)];
    *(bf16x8*)&C[((size_t)by * 128 + row) * NM + bx * 128 + seg * 8] = v;
  }
}

// ---------- top-32 with 128-col tile-max prefilter (unchanged) ----------
#define CAP2 1024
__global__ __launch_bounds__(512) void topk_k(const ushort* __restrict__ scores,
                                              const ushort* __restrict__ tmax,
                                              int srows, int row_base,
                                              const float* __restrict__ temp,
                                              float* __restrict__ attn,
                                              int* __restrict__ idx_out) {
  const int lrow = blockIdx.x;
  const int grow = row_base + lrow;
  const int tid = threadIdx.x;
  const int lane = tid & 63, wid = tid >> 6;
  __shared__ unsigned tlb_s, M_s;
  __shared__ int nqt_s, cnt_s;
  __shared__ ushort qt[NBXT];
  __shared__ unsigned ckey[CAP2];
  __shared__ unsigned cand64[64];
  __shared__ unsigned okey[TOPK];
  __shared__ int oidx[TOPK];

  if (tid == 0) cnt_s = 0;

  if (tid < 64) {
    const unsigned k0 = tmax[(size_t)lane * srows + lrow];
    const unsigned k1 = tmax[(size_t)(lane + 64) * srows + lrow];
    const unsigned k2 = tmax[(size_t)(lane + 128) * srows + lrow];
    const unsigned k3 = tmax[(size_t)(lane + 192) * srows + lrow];
    unsigned mx = max(max(k0, k1), max(k2, k3));
#pragma unroll
    for (int off = 32; off; off >>= 1) mx = max(mx, __shfl_xor(mx, off, 64));
    unsigned lo = 0, hi = mx;
    while (lo < hi) {
      const unsigned mid = (lo + hi + 1) >> 1;
      int c = (int)(k0 >= mid) + (int)(k1 >= mid) + (int)(k2 >= mid) + (int)(k3 >= mid);
#pragma unroll
      for (int off = 32; off; off >>= 1) c += __shfl_xor(c, off, 64);
      if (c >= TOPK) lo = mid; else hi = mid - 1;
    }
    int base = 0;
    {
      const bool p = k0 >= lo;
      const unsigned long long bm = __ballot(p);
      if (p) qt[base + __popcll(bm & ((1ull << lane) - 1ull))] = (ushort)lane;
      base += __popcll(bm);
    }
    {
      const bool p = k1 >= lo;
      const unsigned long long bm = __ballot(p);
      if (p) qt[base + __popcll(bm & ((1ull << lane) - 1ull))] = (ushort)(lane + 64);
      base += __popcll(bm);
    }
    {
      const bool p = k2 >= lo;
      const unsigned long long bm = __ballot(p);
      if (p) qt[base + __popcll(bm & ((1ull << lane) - 1ull))] = (ushort)(lane + 128);
      base += __popcll(bm);
    }
    {
      const bool p = k3 >= lo;
      const unsigned long long bm = __ballot(p);
      if (p) qt[base + __popcll(bm & ((1ull << lane) - 1ull))] = (ushort)(lane + 192);
      base += __popcll(bm);
    }
    if (lane == 0) { nqt_s = base; tlb_s = lo; M_s = mx; }
  }
  __syncthreads();
  const unsigned M = M_s;
  const int nqt = nqt_s;
  unsigned t0 = tlb_s;
  unsigned tlo = t0, thi = M;

  const unsigned* rowu = (const unsigned*)(scores + (size_t)lrow * NM);
  int cnt = 0;
  for (int att = 0; att < 18; ++att) {
    for (int i = wid; i < nqt; i += 8) {
      const int tb = qt[i];
      const unsigned u = rowu[tb * 64 + lane];
      const unsigned m = (u >> 15) & 0x00010001u;
      const unsigned kk = u ^ (m * 0x7FFFu + 0x80008000u);
      const unsigned klo = kk & 0xFFFFu, khi = kk >> 16;
      const int bidx = tb * 128 + lane * 2;
      if (klo >= t0) { const int qq = atomicAdd(&cnt_s, 1); if (qq < CAP2) ckey[qq] = (klo << 16) | (unsigned)(32767 - bidx); }
      if (khi >= t0) { const int qq = atomicAdd(&cnt_s, 1); if (qq < CAP2) ckey[qq] = (khi << 16) | (unsigned)(32767 - (bidx + 1)); }
    }
    __syncthreads();
    cnt = cnt_s;
    __syncthreads();
    if ((cnt >= TOPK && cnt <= CAP2) || att == 17) break;
    if (cnt > CAP2) { tlo = t0; t0 = t0 + ((thi - t0 + 1) >> 1); }
    else { thi = t0; t0 = tlo + ((t0 - tlo) >> 1); }
    if (tid == 0) cnt_s = 0;
    __syncthreads();
  }
  const int n = min(cnt, CAP2);

  if (tid < 64) {
    unsigned lo = t0, hi = M;
    while (lo < hi) {
      const unsigned mid = (lo + hi + 1) >> 1;
      int c = 0;
      for (int i = lane; i < n; i += 64) c += (int)((ckey[i] >> 16) >= mid);
#pragma unroll
      for (int off = 32; off; off >>= 1) c += __shfl_xor(c, off, 64);
      if (c >= TOPK) lo = mid; else hi = mid - 1;
    }
    const unsigned t32 = lo;
    int c32 = 0;
    for (int i = lane; i < n; i += 64) c32 += (int)((ckey[i] >> 16) >= t32);
#pragma unroll
    for (int off = 32; off; off >>= 1) c32 += __shfl_xor(c32, off, 64);

    if (c32 <= 64) {
      cand64[lane] = 0;
      int base = 0;
      for (int r0c = 0; r0c < n; r0c += 64) {
        const int i = r0c + lane;
        const unsigned k = (i < n) ? ckey[i] : 0u;
        const bool p = (k >> 16) >= t32;
        const unsigned long long bm = __ballot(p);
        if (p) {
          const int ps = base + __popcll(bm & ((1ull << lane) - 1ull));
          if (ps < 64) cand64[ps] = k;
        }
        base += __popcll(bm);
      }
      unsigned v = cand64[lane];
#pragma unroll
      for (int k2 = 2; k2 <= 64; k2 <<= 1) {
#pragma unroll
        for (int j = k2 >> 1; j > 0; j >>= 1) {
          const unsigned o = __shfl_xor(v, j, 64);
          const bool lower = (lane & j) == 0;
          const bool descB = (lane & k2) == 0;
          const unsigned mxv = v > o ? v : o;
          const unsigned mnv = v > o ? o : v;
          v = (lower == descB) ? mxv : mnv;
        }
      }
      if (lane < TOPK) {
        okey[lane] = v >> 16;
        oidx[lane] = 32767 - (int)(v & 0x7FFFu);
      }
    } else {
      for (int k = 0; k < TOPK; ++k) {
        unsigned bk = 0;
        for (int j = lane; j < n; j += 64) bk = max(bk, ckey[j]);
#pragma unroll
        for (int off = 32; off; off >>= 1) bk = max(bk, __shfl_xor(bk, off, 64));
        if (lane == 0) {
          okey[k] = bk >> 16;
          oidx[k] = 32767 - (int)(bk & 0x7FFFu);
        }
        for (int j = lane; j < n; j += 64)
          if (ckey[j] == bk) ckey[j] = 0;
      }
    }
  }
  __syncthreads();

  if (tid < TOPK) {
    const float T = fabsf(temp[0]);
    const unsigned k0 = okey[tid];
    const unsigned u0 = (k0 & 0x8000u) ? (k0 ^ 0x8000u) : (k0 ^ 0xFFFFu);
    const unsigned km = okey[0];
    const unsigned um = (km & 0x8000u) ? (km ^ 0x8000u) : (km ^ 0xFFFFu);
    const float s = __uint_as_float(u0 << 16) * T;
    const float mx = __uint_as_float(um << 16) * T;
    const float e = __expf(s - mx);
    float sum = e;
#pragma unroll
    for (int off = 16; off; off >>= 1) sum += __shfl_xor(sum, off, 32);
    attn[(size_t)grow * TOPK + tid] = e / sum;
    idx_out[(size_t)grow * TOPK + tid] = oidx[tid];
  }
}

// ---------- fp8-V gather + residual + LayerNorm, 2 rows/block (unchanged) ----------
__global__ __launch_bounds__(256) void gather_ln_f8(const uchar* __restrict__ V8,
                                                    const float* __restrict__ Q,
                                                    const float* __restrict__ gamma,
                                                    const float* __restrict__ beta,
                                                    const float* __restrict__ attn,
                                                    const int* __restrict__ idx,
                                                    float* __restrict__ out) {
  const int tid = threadIdx.x;
  const int rh = tid >> 7;
  const int t7 = tid & 127;
  const int row = blockIdx.x * 2 + rh;
  __shared__ float a_s[2][TOPK];
  __shared__ int i_s[2][TOPK];
  __shared__ float redS[2][2], redQ[2][2];
  if (t7 < TOPK) {
    a_s[rh][t7] = attn[(size_t)row * TOPK + t7];
    i_s[rh][t7] = idx[(size_t)row * TOPK + t7];
  }
  __syncthreads();

  const int e0 = t7 * 8;
  float acc[8];
#pragma unroll
  for (int u = 0; u < 8; ++u) acc[u] = 0.f;
#pragma unroll
  for (int kb = 0; kb < TOPK; kb += 8) {
    uint2 v[8];
#pragma unroll
    for (int u = 0; u < 8; ++u)
      v[u] = *(const uint2*)&V8[(size_t)i_s[rh][kb + u] * D + e0];
#pragma unroll
    for (int u = 0; u < 8; ++u) {
      const float a = a_s[rh][kb + u];
      acc[0] = fmaf(a, __builtin_amdgcn_cvt_f32_fp8((int)v[u].x, 0), acc[0]);
      acc[1] = fmaf(a, __builtin_amdgcn_cvt_f32_fp8((int)v[u].x, 1), acc[1]);
      acc[2] = fmaf(a, __builtin_amdgcn_cvt_f32_fp8((int)v[u].x, 2), acc[2]);
      acc[3] = fmaf(a, __builtin_amdgcn_cvt_f32_fp8((int)v[u].x, 3), acc[3]);
      acc[4] = fmaf(a, __builtin_amdgcn_cvt_f32_fp8((int)v[u].y, 0), acc[4]);
      acc[5] = fmaf(a, __builtin_amdgcn_cvt_f32_fp8((int)v[u].y, 1), acc[5]);
      acc[6] = fmaf(a, __builtin_amdgcn_cvt_f32_fp8((int)v[u].y, 2), acc[6]);
      acc[7] = fmaf(a, __builtin_amdgcn_cvt_f32_fp8((int)v[u].y, 3), acc[7]);
    }
  }

  const float4 q0 = *(const float4*)&Q[(size_t)row * D + e0];
  const float4 q1 = *(const float4*)&Q[(size_t)row * D + e0 + 4];
  float x[8] = {acc[0] * INV_V8 + q0.x, acc[1] * INV_V8 + q0.y,
                acc[2] * INV_V8 + q0.z, acc[3] * INV_V8 + q0.w,
                acc[4] * INV_V8 + q1.x, acc[5] * INV_V8 + q1.y,
                acc[6] * INV_V8 + q1.z, acc[7] * INV_V8 + q1.w};
  float s = 0.f, ss = 0.f;
#pragma unroll
  for (int c = 0; c < 8; ++c) { s += x[c]; ss += x[c] * x[c]; }
#pragma unroll
  for (int off = 32; off; off >>= 1) {
    s += __shfl_xor(s, off, 64);
    ss += __shfl_xor(ss, off, 64);
  }
  const int w2 = (t7 >> 6);
  if ((tid & 63) == 0) { redS[rh][w2] = s; redQ[rh][w2] = ss; }
  __syncthreads();
  const float S = redS[rh][0] + redS[rh][1];
  const float SS = redQ[rh][0] + redQ[rh][1];
  const float mu = S * (1.0f / D);
  const float var = SS * (1.0f / D) - mu * mu;
  const float rstd = rsqrtf(var + 1e-5f);
  const float4 g0 = *(const float4*)&gamma[e0];
  const float4 g1 = *(const float4*)&gamma[e0 + 4];
  const float4 b0 = *(const float4*)&beta[e0];
  const float4 b1 = *(const float4*)&beta[e0 + 4];
  const float g[8] = {g0.x, g0.y, g0.z, g0.w, g1.x, g1.y, g1.z, g1.w};
  const float b[8] = {b0.x, b0.y, b0.z, b0.w, b1.x, b1.y, b1.z, b1.w};
  float4 o0, o1;
  o0.x = (x[0] - mu) * rstd * g[0] + b[0];
  o0.y = (x[1] - mu) * rstd * g[1] + b[1];
  o0.z = (x[2] - mu) * rstd * g[2] + b[2];
  o0.w = (x[3] - mu) * rstd * g[3] + b[3];
  o1.x = (x[4] - mu) * rstd * g[4] + b[4];
  o1.y = (x[5] - mu) * rstd * g[5] + b[5];
  o1.z = (x[6] - mu) * rstd * g[6] + b[6];
  o1.w = (x[7] - mu) * rstd * g[7] + b[7];
  *(float4*)&out[(size_t)row * D + e0] = o0;
  *(float4*)&out[(size_t)row * D + e0 + 4] = o1;
}

// ---------- fp32 fallback gather ----------
__global__ __launch_bounds__(256) void gather_ln_k(const float* __restrict__ V,
                                                   const float* __restrict__ Q,
                                                   const float* __restrict__ gamma,
                                                   const float* __restrict__ beta,
                                                   const float* __restrict__ attn,
                                                   const int* __restrict__ idx,
                                                   float* __restrict__ out) {
  const int row = blockIdx.x, tid = threadIdx.x;
  __shared__ float a_s[TOPK];
  __shared__ int i_s[TOPK];
  __shared__ float redS[4], redQ[4];
  if (tid < TOPK) {
    a_s[tid] = attn[(size_t)row * TOPK + tid];
    i_s[tid] = idx[(size_t)row * TOPK + tid];
  }
  __syncthreads();
  float4 acc = {0.f, 0.f, 0.f, 0.f};
#pragma unroll
  for (int kb = 0; kb < TOPK; kb += 8) {
    float4 v[8];
#pragma unroll
    for (int u = 0; u < 8; ++u)
      v[u] = ((const float4*)(V + (size_t)i_s[kb + u] * D))[tid];
#pragma unroll
    for (int u = 0; u < 8; ++u) {
      const float a = a_s[kb + u];
      acc.x = fmaf(a, v[u].x, acc.x);
      acc.y = fmaf(a, v[u].y, acc.y);
      acc.z = fmaf(a, v[u].z, acc.z);
      acc.w = fmaf(a, v[u].w, acc.w);
    }
  }
  const float4 q = ((const float4*)(Q + (size_t)row * D))[tid];
  float4 x = {acc.x + q.x, acc.y + q.y, acc.z + q.z, acc.w + q.w};
  float s = x.x + x.y + x.z + x.w;
  float ss = x.x * x.x + x.y * x.y + x.z * x.z + x.w * x.w;
#pragma unroll
  for (int off = 32; off; off >>= 1) {
    s += __shfl_xor(s, off, 64);
    ss += __shfl_xor(ss, off, 64);
  }
  const int wid = tid >> 6, lane = tid & 63;
  if (lane == 0) { redS[wid] = s; redQ[wid] = ss; }
  __syncthreads();
  const float S = redS[0] + redS[1] + redS[2] + redS[3];
  const float SS = redQ[0] + redQ[1] + redQ[2] + redQ[3];
  const float mu = S * (1.0f / D);
  const float var = SS * (1.0f / D) - mu * mu;
  const float rstd = rsqrtf(var + 1e-5f);
  const float4 g = ((const float4*)gamma)[tid];
  const float4 b = ((const float4*)beta)[tid];
  float4 o;
  o.x = (x.x - mu) * rstd * g.x + b.x;
  o.y = (x.y - mu) * rstd * g.y + b.y;
  o.z = (x.z - mu) * rstd * g.z + b.z;
  o.w = (x.w - mu) * rstd * g.w + b.w;
  ((float4*)(out + (size_t)row * D))[tid] = o;
}

extern "C" void kernel_launch(void* const* d_in, const int* in_sizes, int n_in,
                              void* d_out, int out_size, void* d_ws, size_t ws_size,
                              hipStream_t stream) {
  const float* Q = (const float*)d_in[0];
  const float* K = (const float*)d_in[1];
  const float* V = (const float*)d_in[2];
  const float* T = (const float*)d_in[3];
  const float* G = (const float*)d_in[4];
  const float* Bt = (const float*)d_in[5];
  float* out = (float*)d_out;
  float* attn = out + (size_t)NQ * D;

  char* ws = (char*)d_ws;
  const size_t off_q8 = 0;
  const size_t off_k8 = off_q8 + (size_t)NQ * D;                      // 8 MB
  const size_t off_idx = off_k8 + (size_t)NM * D;                     // +32 MB
  const size_t off_tm = off_idx + (size_t)NQ * TOPK * sizeof(int);    // +1 MB
  const size_t off_v8 = off_tm + (size_t)NBXT * 2048 * 2;             // +1 MB
  const size_t v8_bytes = (size_t)NM * D;                             // 32 MB

  const bool use_v8 = ws_size >= off_v8 + v8_bytes + (size_t)256 * NM * 2;
  const size_t off_sc = use_v8 ? off_v8 + v8_bytes : off_v8;

  unsigned* q8 = (unsigned*)(ws + off_q8);
  unsigned* k8 = (unsigned*)(ws + off_k8);
  int* idx = (int*)(ws + off_idx);
  ushort* tm = (ushort*)(ws + off_tm);
  unsigned* v8 = (unsigned*)(ws + off_v8);
  ushort* scores = (ushort*)(ws + off_sc);

  const size_t avail = ws_size > off_sc ? ws_size - off_sc : 0;
  int slice = 2048;
  while (slice > 256 && (size_t)slice * NM * 2ull > avail) slice >>= 1;

  norm_cast8_k<<<NQ, 256, 0, stream>>>(Q, q8);
  norm_cast8_k<<<NM, 256, 0, stream>>>(K, k8);
  if (use_v8) cast_v8_k<<<NM, 256, 0, stream>>>(V, v8);

  const int nbx = NM / 128;
  for (int s0 = 0; s0 < NQ; s0 += slice) {
    const int nby = slice / 128;
    gemm128<<<nbx * nby, 256, 0, stream>>>((const uchar*)q8 + (size_t)s0 * D,
                                           (const uchar*)k8, scores, tm, nby, slice);
    topk_k<<<slice, 512, 0, stream>>>(scores, tm, slice, s0, T, attn, idx);
  }
  if (use_v8)
    gather_ln_f8<<<NQ / 2, 256, 0, stream>>>((const uchar*)v8, Q, G, Bt, attn, idx, out);
  else
    gather_ln_k<<<NQ, 256, 0, stream>>>(V, Q, G, Bt, attn, idx, out);
}

// Round 16
// 610.549 us; speedup vs baseline: 1.2275x; 1.0456x over previous
//
#include <hip/hip_runtime.h>
#include <hip/hip_bf16.h>

#define D 1024
#define NQ 8192
#define NM 32768
#define TOPK 32
#define NBXT 256  // 128-col tiles per row

typedef __attribute__((ext_vector_type(8))) __bf16 bf16x8;
typedef __attribute__((ext_vector_type(4))) float f32x4;
typedef __attribute__((ext_vector_type(2))) long longx2;

__device__ __forceinline__ void load_lds16(const void* g, void* l) {
  __builtin_amdgcn_global_load_lds(
      (const __attribute__((address_space(1))) void*)g,
      (__attribute__((address_space(3))) void*)l, 16, 0, 0);
}

__device__ __forceinline__ ushort f2bf(float f) {
  unsigned u = __float_as_uint(f);
  unsigned r = (u + 0x7FFFu + ((u >> 16) & 1u)) >> 16;
  return (ushort)r;
}
__device__ __forceinline__ unsigned key16(unsigned u) {
  return u ^ ((u & 0x8000u) ? 0xFFFFu : 0x8000u);
}

#define FP8_SCALE 32.0f
#define INV_ACC (1.0f / 1024.0f)  // (1/FP8_SCALE)^2
#define V8_SCALE 16.0f
#define INV_V8 (1.0f / 16.0f)

// ---------- row L2-normalize f32 -> fp8 e4m3 (x32), k-interleaved layout ----------
// Within each 128-elem k-block: granule g=(h*4+l4) (8B) stored at
// G = (h>>1)*8 + l4*2 + (h&1) -> one b128 LDS read = lane's granules for 2 k-steps.
__global__ __launch_bounds__(256) void norm_cast8_k(const float* __restrict__ in,
                                                    unsigned* __restrict__ out8) {
  const int row = blockIdx.x;
  const int tid = threadIdx.x;
  const float4 v = ((const float4*)(in + (size_t)row * D))[tid];
  float ss = v.x * v.x + v.y * v.y + v.z * v.z + v.w * v.w;
#pragma unroll
  for (int off = 32; off; off >>= 1) ss += __shfl_xor(ss, off, 64);
  __shared__ float wsum[4];
  const int wid = tid >> 6, lane = tid & 63;
  if (lane == 0) wsum[wid] = ss;
  __syncthreads();
  const float tot = wsum[0] + wsum[1] + wsum[2] + wsum[3];
  const float inv = FP8_SCALE / fmaxf(sqrtf(tot), 1e-12f);
  int r = __builtin_amdgcn_cvt_pk_fp8_f32(v.x * inv, v.y * inv, 0, false);
  r = __builtin_amdgcn_cvt_pk_fp8_f32(v.z * inv, v.w * inv, r, true);
  const int w5 = tid & 31, blk = tid >> 5;
  const int g = w5 >> 1;
  const int h = g >> 2, l4g = g & 3;
  const int G = (h >> 1) * 8 + l4g * 2 + (h & 1);
  out8[(size_t)row * 256 + blk * 32 + G * 2 + (w5 & 1)] = (unsigned)r;
}

// ---------- plain f32 -> fp8 e4m3 cast (V table, x16, linear layout) ----------
__global__ __launch_bounds__(256) void cast_v8_k(const float* __restrict__ in,
                                                 unsigned* __restrict__ out8) {
  const int row = blockIdx.x;
  const int tid = threadIdx.x;
  const float4 v = ((const float4*)(in + (size_t)row * D))[tid];
  int r = __builtin_amdgcn_cvt_pk_fp8_f32(v.x * V8_SCALE, v.y * V8_SCALE, 0, false);
  r = __builtin_amdgcn_cvt_pk_fp8_f32(v.z * V8_SCALE, v.w * V8_SCALE, r, true);
  out8[(size_t)row * 256 + tid] = (unsigned)r;
}

// ---------- 128x128 fp8 GEMM, BK=128 single-buffer, 4 blocks/CU (R13 verbatim) ----------
// Measured best: 128.3 µs, MfmaUtil 44.6%, SQ_LDS_BANK_CONFLICT = 0.
// R14/R15 dbuf variants measured slower (barrier vmcnt(0) drains the prefetch).
__global__ __launch_bounds__(256, 4) void gemm128(const uchar* __restrict__ A8,
                                                  const uchar* __restrict__ B8,
                                                  ushort* __restrict__ C,
                                                  ushort* __restrict__ TM,
                                                  int nby, int srows) {
  __shared__ alignas(16) ushort lds[16384];  // 32KB: As 16KB | Bs 16KB; C-stage aliases
  __shared__ float wmax[2][128];
  uchar* const As = (uchar*)lds;
  uchar* const Bs = (uchar*)lds + 16384;
  const int tid = threadIdx.x;
  const int lane = tid & 63, wid = tid >> 6;
  const int l15 = lane & 15, l4 = lane >> 4;

  // T1: bijective XCD swizzle
  const int nwg = (int)gridDim.x;
  const int q = nwg >> 3, r = nwg & 7;
  const int xcd = (int)blockIdx.x & 7, pos = (int)blockIdx.x >> 3;
  const int wg = (xcd < r ? xcd * (q + 1) : r * (q + 1) + (xcd - r) * q) + pos;
  const int bx = wg / nby, by = wg % nby;

  const int wr = wid >> 1, wc = wid & 1;  // 2x2 waves, each 64x64 of C

  f32x4 acc[4][4];
#pragma unroll
  for (int m = 0; m < 4; m++)
#pragma unroll
    for (int n = 0; n < 4; n++) acc[m][n] = f32x4{0.f, 0.f, 0.f, 0.f};

  // staging: per tile per operand 128 rows x 8 chunks(16B) = 1024 chunks; thread t,
  // load l covers chunk ci = l*256 + t: row = l*32 + (t>>3), stored s = t&7 holds
  // logical chunk (t&7)^(row&7) (pre-swizzled source; row&7 = (t>>3)&7 for all l).
  const int srow = tid >> 3;
  const int cc = ((tid & 7) ^ ((tid >> 3) & 7)) << 4;
  const uchar* gA = A8 + ((size_t)by * 128 + srow) * 1024 + cc;
  const uchar* gB = B8 + ((size_t)bx * 128 + srow) * 1024 + cc;
  uchar* const ldsA = As + wid * 1024;
  uchar* const ldsB = Bs + wid * 1024;

  // frag reads: logical chunk hp*4+l4 stored at ^(l15&7); b128 = 2 k-steps
  const int ob0 = (((0 + l4) ^ (l15 & 7)) << 4);
  const int ob1 = (((4 + l4) ^ (l15 & 7)) << 4);
  const uchar* const abase = As + (wr * 64 + l15) * 128;
  const uchar* const bbase = Bs + (wc * 64 + l15) * 128;

#pragma unroll 1
  for (int kt = 0; kt < 8; ++kt) {
    const int ko = kt * 128;
#pragma unroll
    for (int l = 0; l < 4; ++l) {
      load_lds16(gA + (size_t)l * 32 * 1024 + ko, ldsA + l * 4096);
      load_lds16(gB + (size_t)l * 32 * 1024 + ko, ldsB + l * 4096);
    }
    __syncthreads();
#pragma unroll
    for (int hp = 0; hp < 2; ++hp) {
      const int ob = hp ? ob1 : ob0;
      longx2 af[4], bfv[4];
#pragma unroll
      for (int m = 0; m < 4; ++m) af[m] = *(const longx2*)(abase + m * 2048 + ob);
#pragma unroll
      for (int n = 0; n < 4; ++n) bfv[n] = *(const longx2*)(bbase + n * 2048 + ob);
#pragma unroll
      for (int m = 0; m < 4; ++m)
#pragma unroll
        for (int n = 0; n < 4; ++n) {
          acc[m][n] = __builtin_amdgcn_mfma_f32_16x16x32_fp8_fp8(af[m].x, bfv[n].x, acc[m][n], 0, 0, 0);
          acc[m][n] = __builtin_amdgcn_mfma_f32_16x16x32_fp8_fp8(af[m].y, bfv[n].y, acc[m][n], 0, 0, 0);
        }
    }
    __syncthreads();
  }

  // epilogue 1: per-row max over this block's 128 cols (atomic-free); scale acc
#pragma unroll
  for (int m = 0; m < 4; ++m)
#pragma unroll
    for (int j = 0; j < 4; ++j) {
      float fm = fmaxf(fmaxf(acc[m][0][j], acc[m][1][j]), fmaxf(acc[m][2][j], acc[m][3][j]));
#pragma unroll
      for (int off = 1; off < 16; off <<= 1) fm = fmaxf(fm, __shfl_xor(fm, off, 64));
      if (l15 == 0) wmax[wc][wr * 64 + l4 * 4 + m * 16 + j] = fm;
    }
  __syncthreads();
  if (tid < 128) {
    const float fm = fmaxf(wmax[0][tid], wmax[1][tid]) * INV_ACC;
    TM[(size_t)bx * srows + by * 128 + tid] = (ushort)key16((unsigned)f2bf(fm));
  }

  // epilogue 2: stage C-tile to LDS (chunk-XOR swizzle), stream out coalesced.
#pragma unroll
  for (int m = 0; m < 4; ++m)
#pragma unroll
    for (int n = 0; n < 4; ++n) {
      const int col = wc * 64 + n * 16 + l15;
      const int c8 = col >> 3, c7 = col & 7;
#pragma unroll
      for (int j = 0; j < 4; ++j) {
        const int row = wr * 64 + m * 16 + l4 * 4 + j;
        lds[row * 128 + ((c8 ^ (row & 7)) << 3) + c7] = f2bf(acc[m][n][j] * INV_ACC);
      }
    }
  __syncthreads();
  const int orow = tid >> 4, seg = tid & 15;
#pragma unroll
  for (int p = 0; p < 8; ++p) {
    const int row = p * 16 + orow;
    const bf16x8 v = *(const bf16x8*)&lds[row * 128 + ((seg ^ (row & 7)) << 3)];
    *(bf16x8*)&C[((size_t)by * 128 + row) * NM + bx * 128 + seg * 8] = v;
  }
}

// ---------- top-32 with 128-col tile-max prefilter (unchanged) ----------
#define CAP2 1024
__global__ __launch_bounds__(512) void topk_k(const ushort* __restrict__ scores,
                                              const ushort* __restrict__ tmax,
                                              int srows, int row_base,
                                              const float* __restrict__ temp,
                                              float* __restrict__ attn,
                                              int* __restrict__ idx_out) {
  const int lrow = blockIdx.x;
  const int grow = row_base + lrow;
  const int tid = threadIdx.x;
  const int lane = tid & 63, wid = tid >> 6;
  __shared__ unsigned tlb_s, M_s;
  __shared__ int nqt_s, cnt_s;
  __shared__ ushort qt[NBXT];
  __shared__ unsigned ckey[CAP2];
  __shared__ unsigned cand64[64];
  __shared__ unsigned okey[TOPK];
  __shared__ int oidx[TOPK];

  if (tid == 0) cnt_s = 0;

  if (tid < 64) {
    const unsigned k0 = tmax[(size_t)lane * srows + lrow];
    const unsigned k1 = tmax[(size_t)(lane + 64) * srows + lrow];
    const unsigned k2 = tmax[(size_t)(lane + 128) * srows + lrow];
    const unsigned k3 = tmax[(size_t)(lane + 192) * srows + lrow];
    unsigned mx = max(max(k0, k1), max(k2, k3));
#pragma unroll
    for (int off = 32; off; off >>= 1) mx = max(mx, __shfl_xor(mx, off, 64));
    unsigned lo = 0, hi = mx;
    while (lo < hi) {
      const unsigned mid = (lo + hi + 1) >> 1;
      int c = (int)(k0 >= mid) + (int)(k1 >= mid) + (int)(k2 >= mid) + (int)(k3 >= mid);
#pragma unroll
      for (int off = 32; off; off >>= 1) c += __shfl_xor(c, off, 64);
      if (c >= TOPK) lo = mid; else hi = mid - 1;
    }
    int base = 0;
    {
      const bool p = k0 >= lo;
      const unsigned long long bm = __ballot(p);
      if (p) qt[base + __popcll(bm & ((1ull << lane) - 1ull))] = (ushort)lane;
      base += __popcll(bm);
    }
    {
      const bool p = k1 >= lo;
      const unsigned long long bm = __ballot(p);
      if (p) qt[base + __popcll(bm & ((1ull << lane) - 1ull))] = (ushort)(lane + 64);
      base += __popcll(bm);
    }
    {
      const bool p = k2 >= lo;
      const unsigned long long bm = __ballot(p);
      if (p) qt[base + __popcll(bm & ((1ull << lane) - 1ull))] = (ushort)(lane + 128);
      base += __popcll(bm);
    }
    {
      const bool p = k3 >= lo;
      const unsigned long long bm = __ballot(p);
      if (p) qt[base + __popcll(bm & ((1ull << lane) - 1ull))] = (ushort)(lane + 192);
      base += __popcll(bm);
    }
    if (lane == 0) { nqt_s = base; tlb_s = lo; M_s = mx; }
  }
  __syncthreads();
  const unsigned M = M_s;
  const int nqt = nqt_s;
  unsigned t0 = tlb_s;
  unsigned tlo = t0, thi = M;

  const unsigned* rowu = (const unsigned*)(scores + (size_t)lrow * NM);
  int cnt = 0;
  for (int att = 0; att < 18; ++att) {
    for (int i = wid; i < nqt; i += 8) {
      const int tb = qt[i];
      const unsigned u = rowu[tb * 64 + lane];
      const unsigned m = (u >> 15) & 0x00010001u;
      const unsigned kk = u ^ (m * 0x7FFFu + 0x80008000u);
      const unsigned klo = kk & 0xFFFFu, khi = kk >> 16;
      const int bidx = tb * 128 + lane * 2;
      if (klo >= t0) { const int qq = atomicAdd(&cnt_s, 1); if (qq < CAP2) ckey[qq] = (klo << 16) | (unsigned)(32767 - bidx); }
      if (khi >= t0) { const int qq = atomicAdd(&cnt_s, 1); if (qq < CAP2) ckey[qq] = (khi << 16) | (unsigned)(32767 - (bidx + 1)); }
    }
    __syncthreads();
    cnt = cnt_s;
    __syncthreads();
    if ((cnt >= TOPK && cnt <= CAP2) || att == 17) break;
    if (cnt > CAP2) { tlo = t0; t0 = t0 + ((thi - t0 + 1) >> 1); }
    else { thi = t0; t0 = tlo + ((t0 - tlo) >> 1); }
    if (tid == 0) cnt_s = 0;
    __syncthreads();
  }
  const int n = min(cnt, CAP2);

  if (tid < 64) {
    unsigned lo = t0, hi = M;
    while (lo < hi) {
      const unsigned mid = (lo + hi + 1) >> 1;
      int c = 0;
      for (int i = lane; i < n; i += 64) c += (int)((ckey[i] >> 16) >= mid);
#pragma unroll
      for (int off = 32; off; off >>= 1) c += __shfl_xor(c, off, 64);
      if (c >= TOPK) lo = mid; else hi = mid - 1;
    }
    const unsigned t32 = lo;
    int c32 = 0;
    for (int i = lane; i < n; i += 64) c32 += (int)((ckey[i] >> 16) >= t32);
#pragma unroll
    for (int off = 32; off; off >>= 1) c32 += __shfl_xor(c32, off, 64);

    if (c32 <= 64) {
      cand64[lane] = 0;
      int base = 0;
      for (int r0c = 0; r0c < n; r0c += 64) {
        const int i = r0c + lane;
        const unsigned k = (i < n) ? ckey[i] : 0u;
        const bool p = (k >> 16) >= t32;
        const unsigned long long bm = __ballot(p);
        if (p) {
          const int ps = base + __popcll(bm & ((1ull << lane) - 1ull));
          if (ps < 64) cand64[ps] = k;
        }
        base += __popcll(bm);
      }
      unsigned v = cand64[lane];
#pragma unroll
      for (int k2 = 2; k2 <= 64; k2 <<= 1) {
#pragma unroll
        for (int j = k2 >> 1; j > 0; j >>= 1) {
          const unsigned o = __shfl_xor(v, j, 64);
          const bool lower = (lane & j) == 0;
          const bool descB = (lane & k2) == 0;
          const unsigned mxv = v > o ? v : o;
          const unsigned mnv = v > o ? o : v;
          v = (lower == descB) ? mxv : mnv;
        }
      }
      if (lane < TOPK) {
        okey[lane] = v >> 16;
        oidx[lane] = 32767 - (int)(v & 0x7FFFu);
      }
    } else {
      for (int k = 0; k < TOPK; ++k) {
        unsigned bk = 0;
        for (int j = lane; j < n; j += 64) bk = max(bk, ckey[j]);
#pragma unroll
        for (int off = 32; off; off >>= 1) bk = max(bk, __shfl_xor(bk, off, 64));
        if (lane == 0) {
          okey[k] = bk >> 16;
          oidx[k] = 32767 - (int)(bk & 0x7FFFu);
        }
        for (int j = lane; j < n; j += 64)
          if (ckey[j] == bk) ckey[j] = 0;
      }
    }
  }
  __syncthreads();

  if (tid < TOPK) {
    const float T = fabsf(temp[0]);
    const unsigned k0 = okey[tid];
    const unsigned u0 = (k0 & 0x8000u) ? (k0 ^ 0x8000u) : (k0 ^ 0xFFFFu);
    const unsigned km = okey[0];
    const unsigned um = (km & 0x8000u) ? (km ^ 0x8000u) : (km ^ 0xFFFFu);
    const float s = __uint_as_float(u0 << 16) * T;
    const float mx = __uint_as_float(um << 16) * T;
    const float e = __expf(s - mx);
    float sum = e;
#pragma unroll
    for (int off = 16; off; off >>= 1) sum += __shfl_xor(sum, off, 32);
    attn[(size_t)grow * TOPK + tid] = e / sum;
    idx_out[(size_t)grow * TOPK + tid] = oidx[tid];
  }
}

// ---------- fp8-V gather + residual + LayerNorm, 2 rows/block (unchanged) ----------
__global__ __launch_bounds__(256) void gather_ln_f8(const uchar* __restrict__ V8,
                                                    const float* __restrict__ Q,
                                                    const float* __restrict__ gamma,
                                                    const float* __restrict__ beta,
                                                    const float* __restrict__ attn,
                                                    const int* __restrict__ idx,
                                                    float* __restrict__ out) {
  const int tid = threadIdx.x;
  const int rh = tid >> 7;
  const int t7 = tid & 127;
  const int row = blockIdx.x * 2 + rh;
  __shared__ float a_s[2][TOPK];
  __shared__ int i_s[2][TOPK];
  __shared__ float redS[2][2], redQ[2][2];
  if (t7 < TOPK) {
    a_s[rh][t7] = attn[(size_t)row * TOPK + t7];
    i_s[rh][t7] = idx[(size_t)row * TOPK + t7];
  }
  __syncthreads();

  const int e0 = t7 * 8;
  float acc[8];
#pragma unroll
  for (int u = 0; u < 8; ++u) acc[u] = 0.f;
#pragma unroll
  for (int kb = 0; kb < TOPK; kb += 8) {
    uint2 v[8];
#pragma unroll
    for (int u = 0; u < 8; ++u)
      v[u] = *(const uint2*)&V8[(size_t)i_s[rh][kb + u] * D + e0];
#pragma unroll
    for (int u = 0; u < 8; ++u) {
      const float a = a_s[rh][kb + u];
      acc[0] = fmaf(a, __builtin_amdgcn_cvt_f32_fp8((int)v[u].x, 0), acc[0]);
      acc[1] = fmaf(a, __builtin_amdgcn_cvt_f32_fp8((int)v[u].x, 1), acc[1]);
      acc[2] = fmaf(a, __builtin_amdgcn_cvt_f32_fp8((int)v[u].x, 2), acc[2]);
      acc[3] = fmaf(a, __builtin_amdgcn_cvt_f32_fp8((int)v[u].x, 3), acc[3]);
      acc[4] = fmaf(a, __builtin_amdgcn_cvt_f32_fp8((int)v[u].y, 0), acc[4]);
      acc[5] = fmaf(a, __builtin_amdgcn_cvt_f32_fp8((int)v[u].y, 1), acc[5]);
      acc[6] = fmaf(a, __builtin_amdgcn_cvt_f32_fp8((int)v[u].y, 2), acc[6]);
      acc[7] = fmaf(a, __builtin_amdgcn_cvt_f32_fp8((int)v[u].y, 3), acc[7]);
    }
  }

  const float4 q0 = *(const float4*)&Q[(size_t)row * D + e0];
  const float4 q1 = *(const float4*)&Q[(size_t)row * D + e0 + 4];
  float x[8] = {acc[0] * INV_V8 + q0.x, acc[1] * INV_V8 + q0.y,
                acc[2] * INV_V8 + q0.z, acc[3] * INV_V8 + q0.w,
                acc[4] * INV_V8 + q1.x, acc[5] * INV_V8 + q1.y,
                acc[6] * INV_V8 + q1.z, acc[7] * INV_V8 + q1.w};
  float s = 0.f, ss = 0.f;
#pragma unroll
  for (int c = 0; c < 8; ++c) { s += x[c]; ss += x[c] * x[c]; }
#pragma unroll
  for (int off = 32; off; off >>= 1) {
    s += __shfl_xor(s, off, 64);
    ss += __shfl_xor(ss, off, 64);
  }
  const int w2 = (t7 >> 6);
  if ((tid & 63) == 0) { redS[rh][w2] = s; redQ[rh][w2] = ss; }
  __syncthreads();
  const float S = redS[rh][0] + redS[rh][1];
  const float SS = redQ[rh][0] + redQ[rh][1];
  const float mu = S * (1.0f / D);
  const float var = SS * (1.0f / D) - mu * mu;
  const float rstd = rsqrtf(var + 1e-5f);
  const float4 g0 = *(const float4*)&gamma[e0];
  const float4 g1 = *(const float4*)&gamma[e0 + 4];
  const float4 b0 = *(const float4*)&beta[e0];
  const float4 b1 = *(const float4*)&beta[e0 + 4];
  const float g[8] = {g0.x, g0.y, g0.z, g0.w, g1.x, g1.y, g1.z, g1.w};
  const float b[8] = {b0.x, b0.y, b0.z, b0.w, b1.x, b1.y, b1.z, b1.w};
  float4 o0, o1;
  o0.x = (x[0] - mu) * rstd * g[0] + b[0];
  o0.y = (x[1] - mu) * rstd * g[1] + b[1];
  o0.z = (x[2] - mu) * rstd * g[2] + b[2];
  o0.w = (x[3] - mu) * rstd * g[3] + b[3];
  o1.x = (x[4] - mu) * rstd * g[4] + b[4];
  o1.y = (x[5] - mu) * rstd * g[5] + b[5];
  o1.z = (x[6] - mu) * rstd * g[6] + b[6];
  o1.w = (x[7] - mu) * rstd * g[7] + b[7];
  *(float4*)&out[(size_t)row * D + e0] = o0;
  *(float4*)&out[(size_t)row * D + e0 + 4] = o1;
}

// ---------- fp32 fallback gather ----------
__global__ __launch_bounds__(256) void gather_ln_k(const float* __restrict__ V,
                                                   const float* __restrict__ Q,
                                                   const float* __restrict__ gamma,
                                                   const float* __restrict__ beta,
                                                   const float* __restrict__ attn,
                                                   const int* __restrict__ idx,
                                                   float* __restrict__ out) {
  const int row = blockIdx.x, tid = threadIdx.x;
  __shared__ float a_s[TOPK];
  __shared__ int i_s[TOPK];
  __shared__ float redS[4], redQ[4];
  if (tid < TOPK) {
    a_s[tid] = attn[(size_t)row * TOPK + tid];
    i_s[tid] = idx[(size_t)row * TOPK + tid];
  }
  __syncthreads();
  float4 acc = {0.f, 0.f, 0.f, 0.f};
#pragma unroll
  for (int kb = 0; kb < TOPK; kb += 8) {
    float4 v[8];
#pragma unroll
    for (int u = 0; u < 8; ++u)
      v[u] = ((const float4*)(V + (size_t)i_s[kb + u] * D))[tid];
#pragma unroll
    for (int u = 0; u < 8; ++u) {
      const float a = a_s[kb + u];
      acc.x = fmaf(a, v[u].x, acc.x);
      acc.y = fmaf(a, v[u].y, acc.y);
      acc.z = fmaf(a, v[u].z, acc.z);
      acc.w = fmaf(a, v[u].w, acc.w);
    }
  }
  const float4 q = ((const float4*)(Q + (size_t)row * D))[tid];
  float4 x = {acc.x + q.x, acc.y + q.y, acc.z + q.z, acc.w + q.w};
  float s = x.x + x.y + x.z + x.w;
  float ss = x.x * x.x + x.y * x.y + x.z * x.z + x.w * x.w;
#pragma unroll
  for (int off = 32; off; off >>= 1) {
    s += __shfl_xor(s, off, 64);
    ss += __shfl_xor(ss, off, 64);
  }
  const int wid = tid >> 6, lane = tid & 63;
  if (lane == 0) { redS[wid] = s; redQ[wid] = ss; }
  __syncthreads();
  const float S = redS[0] + redS[1] + redS[2] + redS[3];
  const float SS = redQ[0] + redQ[1] + redQ[2] + redQ[3];
  const float mu = S * (1.0f / D);
  const float var = SS * (1.0f / D) - mu * mu;
  const float rstd = rsqrtf(var + 1e-5f);
  const float4 g = ((const float4*)gamma)[tid];
  const float4 b = ((const float4*)beta)[tid];
  float4 o;
  o.x = (x.x - mu) * rstd * g.x + b.x;
  o.y = (x.y - mu) * rstd * g.y + b.y;
  o.z = (x.z - mu) * rstd * g.z + b.z;
  o.w = (x.w - mu) * rstd * g.w + b.w;
  ((float4*)(out + (size_t)row * D))[tid] = o;
}

extern "C" void kernel_launch(void* const* d_in, const int* in_sizes, int n_in,
                              void* d_out, int out_size, void* d_ws, size_t ws_size,
                              hipStream_t stream) {
  const float* Q = (const float*)d_in[0];
  const float* K = (const float*)d_in[1];
  const float* V = (const float*)d_in[2];
  const float* T = (const float*)d_in[3];
  const float* G = (const float*)d_in[4];
  const float* Bt = (const float*)d_in[5];
  float* out = (float*)d_out;
  float* attn = out + (size_t)NQ * D;

  char* ws = (char*)d_ws;
  const size_t off_q8 = 0;
  const size_t off_k8 = off_q8 + (size_t)NQ * D;                      // 8 MB
  const size_t off_idx = off_k8 + (size_t)NM * D;                     // +32 MB
  const size_t off_tm = off_idx + (size_t)NQ * TOPK * sizeof(int);    // +1 MB
  const size_t off_v8 = off_tm + (size_t)NBXT * 2048 * 2;             // +1 MB
  const size_t v8_bytes = (size_t)NM * D;                             // 32 MB

  const bool use_v8 = ws_size >= off_v8 + v8_bytes + (size_t)256 * NM * 2;
  const size_t off_sc = use_v8 ? off_v8 + v8_bytes : off_v8;

  unsigned* q8 = (unsigned*)(ws + off_q8);
  unsigned* k8 = (unsigned*)(ws + off_k8);
  int* idx = (int*)(ws + off_idx);
  ushort* tm = (ushort*)(ws + off_tm);
  unsigned* v8 = (unsigned*)(ws + off_v8);
  ushort* scores = (ushort*)(ws + off_sc);

  const size_t avail = ws_size > off_sc ? ws_size - off_sc : 0;
  int slice = 2048;
  while (slice > 256 && (size_t)slice * NM * 2ull > avail) slice >>= 1;

  norm_cast8_k<<<NQ, 256, 0, stream>>>(Q, q8);
  norm_cast8_k<<<NM, 256, 0, stream>>>(K, k8);
  if (use_v8) cast_v8_k<<<NM, 256, 0, stream>>>(V, v8);

  const int nbx = NM / 128;
  for (int s0 = 0; s0 < NQ; s0 += slice) {
    const int nby = slice / 128;
    gemm128<<<nbx * nby, 256, 0, stream>>>((const uchar*)q8 + (size_t)s0 * D,
                                           (const uchar*)k8, scores, tm, nby, slice);
    topk_k<<<slice, 512, 0, stream>>>(scores, tm, slice, s0, T, attn, idx);
  }
  if (use_v8)
    gather_ln_f8<<<NQ / 2, 256, 0, stream>>>((const uchar*)v8, Q, G, Bt, attn, idx, out);
  else
    gather_ln_k<<<NQ, 256, 0, stream>>>(V, Q, G, Bt, attn, idx, out);
}

// Round 17
// 592.392 us; speedup vs baseline: 1.2651x; 1.0306x over previous
//
#include <hip/hip_runtime.h>
#include <hip/hip_bf16.h>

#define D 1024
#define NQ 8192
#define NM 32768
#define TOPK 32
#define NBXT 256  // 128-col tiles per row

typedef __attribute__((ext_vector_type(8))) __bf16 bf16x8;
typedef __attribute__((ext_vector_type(4))) float f32x4;
typedef __attribute__((ext_vector_type(4))) int i32x4;
typedef __attribute__((ext_vector_type(8))) int i32x8;

__device__ __forceinline__ void load_lds16(const void* g, void* l) {
  __builtin_amdgcn_global_load_lds(
      (const __attribute__((address_space(1))) void*)g,
      (__attribute__((address_space(3))) void*)l, 16, 0, 0);
}

__device__ __forceinline__ ushort f2bf(float f) {
  unsigned u = __float_as_uint(f);
  unsigned r = (u + 0x7FFFu + ((u >> 16) & 1u)) >> 16;
  return (ushort)r;
}
__device__ __forceinline__ unsigned key16(unsigned u) {
  return u ^ ((u & 0x8000u) ? 0xFFFFu : 0x8000u);
}

#define FP8_SCALE 32.0f
#define INV_ACC (1.0f / 1024.0f)  // (1/FP8_SCALE)^2
#define V8_SCALE 16.0f
#define INV_V8 (1.0f / 16.0f)
#define SCALE_ONE 0x7F7F7F7F      // e8m0 1.0 in all 4 bytes

// ---------- row L2-normalize f32 -> fp8 e4m3 (x32), LINEAR row-major ----------
// K=128 scaled MFMA wants lane(l4) k = l4*32+[0..32) contiguous -> no interleave.
__global__ __launch_bounds__(256) void norm_cast8_k(const float* __restrict__ in,
                                                    unsigned* __restrict__ out8) {
  const int row = blockIdx.x;
  const int tid = threadIdx.x;
  const float4 v = ((const float4*)(in + (size_t)row * D))[tid];
  float ss = v.x * v.x + v.y * v.y + v.z * v.z + v.w * v.w;
#pragma unroll
  for (int off = 32; off; off >>= 1) ss += __shfl_xor(ss, off, 64);
  __shared__ float wsum[4];
  const int wid = tid >> 6, lane = tid & 63;
  if (lane == 0) wsum[wid] = ss;
  __syncthreads();
  const float tot = wsum[0] + wsum[1] + wsum[2] + wsum[3];
  const float inv = FP8_SCALE / fmaxf(sqrtf(tot), 1e-12f);
  int r = __builtin_amdgcn_cvt_pk_fp8_f32(v.x * inv, v.y * inv, 0, false);
  r = __builtin_amdgcn_cvt_pk_fp8_f32(v.z * inv, v.w * inv, r, true);
  out8[(size_t)row * 256 + tid] = (unsigned)r;
}

// ---------- plain f32 -> fp8 e4m3 cast (V table, x16, linear layout) ----------
__global__ __launch_bounds__(256) void cast_v8_k(const float* __restrict__ in,
                                                 unsigned* __restrict__ out8) {
  const int row = blockIdx.x;
  const int tid = threadIdx.x;
  const float4 v = ((const float4*)(in + (size_t)row * D))[tid];
  int r = __builtin_amdgcn_cvt_pk_fp8_f32(v.x * V8_SCALE, v.y * V8_SCALE, 0, false);
  r = __builtin_amdgcn_cvt_pk_fp8_f32(v.z * V8_SCALE, v.w * V8_SCALE, r, true);
  out8[(size_t)row * 256 + tid] = (unsigned)r;
}

// ---------- 128x128 fp8 GEMM, BK=128, MX-scaled K=128 MFMA (scale=1.0) ----------
// R13/R16 sync structure and staging verbatim; inner loop = 16 scaled MFMA
// (mfma_scale_f32_16x16x128_f8f6f4, cbsz=blgp=0 e4m3) instead of 64 K=32 ops.
__global__ __launch_bounds__(256, 4) void gemm128(const uchar* __restrict__ A8,
                                                  const uchar* __restrict__ B8,
                                                  ushort* __restrict__ C,
                                                  ushort* __restrict__ TM,
                                                  int nby, int srows) {
  __shared__ alignas(16) ushort lds[16384];  // 32KB: As 16KB | Bs 16KB; C-stage aliases
  __shared__ float wmax[2][128];
  uchar* const As = (uchar*)lds;
  uchar* const Bs = (uchar*)lds + 16384;
  const int tid = threadIdx.x;
  const int lane = tid & 63, wid = tid >> 6;
  const int l15 = lane & 15, l4 = lane >> 4;

  // T1: bijective XCD swizzle
  const int nwg = (int)gridDim.x;
  const int q = nwg >> 3, r = nwg & 7;
  const int xcd = (int)blockIdx.x & 7, pos = (int)blockIdx.x >> 3;
  const int wg = (xcd < r ? xcd * (q + 1) : r * (q + 1) + (xcd - r) * q) + pos;
  const int bx = wg / nby, by = wg % nby;

  const int wr = wid >> 1, wc = wid & 1;  // 2x2 waves, each 64x64 of C

  f32x4 acc[4][4];
#pragma unroll
  for (int m = 0; m < 4; m++)
#pragma unroll
    for (int n = 0; n < 4; n++) acc[m][n] = f32x4{0.f, 0.f, 0.f, 0.f};

  // staging (R13 verbatim): 1024 chunks(16B)/operand/tile; thread t, load l:
  // chunk ci = l*256 + t -> row = l*32 + (t>>3); stored slot t&7 holds logical
  // chunk (t&7)^(row&7) (pre-swizzled source, linear LDS dest).
  const int srow = tid >> 3;
  const int cc = ((tid & 7) ^ ((tid >> 3) & 7)) << 4;
  const uchar* gA = A8 + ((size_t)by * 128 + srow) * 1024 + cc;
  const uchar* gB = B8 + ((size_t)bx * 128 + srow) * 1024 + cc;
  uchar* const ldsA = As + wid * 1024;
  uchar* const ldsB = Bs + wid * 1024;

  // frag reads: lane's 32B = logical chunks 2l4, 2l4+1, stored at ^(l15&7)
  const int ob0 = (((2 * l4 + 0) ^ (l15 & 7)) << 4);
  const int ob1 = (((2 * l4 + 1) ^ (l15 & 7)) << 4);
  const uchar* const abase = As + (wr * 64 + l15) * 128;
  const uchar* const bbase = Bs + (wc * 64 + l15) * 128;

#pragma unroll 1
  for (int kt = 0; kt < 8; ++kt) {
    const int ko = kt * 128;
#pragma unroll
    for (int l = 0; l < 4; ++l) {
      load_lds16(gA + (size_t)l * 32 * 1024 + ko, ldsA + l * 4096);
      load_lds16(gB + (size_t)l * 32 * 1024 + ko, ldsB + l * 4096);
    }
    __syncthreads();
    i32x8 af[4], bfv[4];
#pragma unroll
    for (int m = 0; m < 4; ++m) {
      const i32x4 lo = *(const i32x4*)(abase + m * 2048 + ob0);
      const i32x4 hi = *(const i32x4*)(abase + m * 2048 + ob1);
      af[m] = (i32x8){lo[0], lo[1], lo[2], lo[3], hi[0], hi[1], hi[2], hi[3]};
    }
#pragma unroll
    for (int n = 0; n < 4; ++n) {
      const i32x4 lo = *(const i32x4*)(bbase + n * 2048 + ob0);
      const i32x4 hi = *(const i32x4*)(bbase + n * 2048 + ob1);
      bfv[n] = (i32x8){lo[0], lo[1], lo[2], lo[3], hi[0], hi[1], hi[2], hi[3]};
    }
#pragma unroll
    for (int m = 0; m < 4; ++m)
#pragma unroll
      for (int n = 0; n < 4; ++n)
        acc[m][n] = __builtin_amdgcn_mfma_scale_f32_16x16x128_f8f6f4(
            af[m], bfv[n], acc[m][n], 0, 0, 0, SCALE_ONE, 0, SCALE_ONE);
    __syncthreads();
  }

  // epilogue 1: per-row max over this block's 128 cols (atomic-free); scale acc
#pragma unroll
  for (int m = 0; m < 4; ++m)
#pragma unroll
    for (int j = 0; j < 4; ++j) {
      float fm = fmaxf(fmaxf(acc[m][0][j], acc[m][1][j]), fmaxf(acc[m][2][j], acc[m][3][j]));
#pragma unroll
      for (int off = 1; off < 16; off <<= 1) fm = fmaxf(fm, __shfl_xor(fm, off, 64));
      if (l15 == 0) wmax[wc][wr * 64 + l4 * 4 + m * 16 + j] = fm;
    }
  __syncthreads();
  if (tid < 128) {
    const float fm = fmaxf(wmax[0][tid], wmax[1][tid]) * INV_ACC;
    TM[(size_t)bx * srows + by * 128 + tid] = (ushort)key16((unsigned)f2bf(fm));
  }

  // epilogue 2: stage C-tile to LDS (chunk-XOR swizzle), stream out coalesced.
#pragma unroll
  for (int m = 0; m < 4; ++m)
#pragma unroll
    for (int n = 0; n < 4; ++n) {
      const int col = wc * 64 + n * 16 + l15;
      const int c8 = col >> 3, c7 = col & 7;
#pragma unroll
      for (int j = 0; j < 4; ++j) {
        const int row = wr * 64 + m * 16 + l4 * 4 + j;
        lds[row * 128 + ((c8 ^ (row & 7)) << 3) + c7] = f2bf(acc[m][n][j] * INV_ACC);
      }
    }
  __syncthreads();
  const int orow = tid >> 4, seg = tid & 15;
#pragma unroll
  for (int p = 0; p < 8; ++p) {
    const int row = p * 16 + orow;
    const bf16x8 v = *(const bf16x8*)&lds[row * 128 + ((seg ^ (row & 7)) << 3)];
    *(bf16x8*)&C[((size_t)by * 128 + row) * NM + bx * 128 + seg * 8] = v;
  }
}

// ---------- top-32 with 128-col tile-max prefilter (unchanged) ----------
#define CAP2 1024
__global__ __launch_bounds__(512) void topk_k(const ushort* __restrict__ scores,
                                              const ushort* __restrict__ tmax,
                                              int srows, int row_base,
                                              const float* __restrict__ temp,
                                              float* __restrict__ attn,
                                              int* __restrict__ idx_out) {
  const int lrow = blockIdx.x;
  const int grow = row_base + lrow;
  const int tid = threadIdx.x;
  const int lane = tid & 63, wid = tid >> 6;
  __shared__ unsigned tlb_s, M_s;
  __shared__ int nqt_s, cnt_s;
  __shared__ ushort qt[NBXT];
  __shared__ unsigned ckey[CAP2];
  __shared__ unsigned cand64[64];
  __shared__ unsigned okey[TOPK];
  __shared__ int oidx[TOPK];

  if (tid == 0) cnt_s = 0;

  if (tid < 64) {
    const unsigned k0 = tmax[(size_t)lane * srows + lrow];
    const unsigned k1 = tmax[(size_t)(lane + 64) * srows + lrow];
    const unsigned k2 = tmax[(size_t)(lane + 128) * srows + lrow];
    const unsigned k3 = tmax[(size_t)(lane + 192) * srows + lrow];
    unsigned mx = max(max(k0, k1), max(k2, k3));
#pragma unroll
    for (int off = 32; off; off >>= 1) mx = max(mx, __shfl_xor(mx, off, 64));
    unsigned lo = 0, hi = mx;
    while (lo < hi) {
      const unsigned mid = (lo + hi + 1) >> 1;
      int c = (int)(k0 >= mid) + (int)(k1 >= mid) + (int)(k2 >= mid) + (int)(k3 >= mid);
#pragma unroll
      for (int off = 32; off; off >>= 1) c += __shfl_xor(c, off, 64);
      if (c >= TOPK) lo = mid; else hi = mid - 1;
    }
    int base = 0;
    {
      const bool p = k0 >= lo;
      const unsigned long long bm = __ballot(p);
      if (p) qt[base + __popcll(bm & ((1ull << lane) - 1ull))] = (ushort)lane;
      base += __popcll(bm);
    }
    {
      const bool p = k1 >= lo;
      const unsigned long long bm = __ballot(p);
      if (p) qt[base + __popcll(bm & ((1ull << lane) - 1ull))] = (ushort)(lane + 64);
      base += __popcll(bm);
    }
    {
      const bool p = k2 >= lo;
      const unsigned long long bm = __ballot(p);
      if (p) qt[base + __popcll(bm & ((1ull << lane) - 1ull))] = (ushort)(lane + 128);
      base += __popcll(bm);
    }
    {
      const bool p = k3 >= lo;
      const unsigned long long bm = __ballot(p);
      if (p) qt[base + __popcll(bm & ((1ull << lane) - 1ull))] = (ushort)(lane + 192);
      base += __popcll(bm);
    }
    if (lane == 0) { nqt_s = base; tlb_s = lo; M_s = mx; }
  }
  __syncthreads();
  const unsigned M = M_s;
  const int nqt = nqt_s;
  unsigned t0 = tlb_s;
  unsigned tlo = t0, thi = M;

  const unsigned* rowu = (const unsigned*)(scores + (size_t)lrow * NM);
  int cnt = 0;
  for (int att = 0; att < 18; ++att) {
    for (int i = wid; i < nqt; i += 8) {
      const int tb = qt[i];
      const unsigned u = rowu[tb * 64 + lane];
      const unsigned m = (u >> 15) & 0x00010001u;
      const unsigned kk = u ^ (m * 0x7FFFu + 0x80008000u);
      const unsigned klo = kk & 0xFFFFu, khi = kk >> 16;
      const int bidx = tb * 128 + lane * 2;
      if (klo >= t0) { const int qq = atomicAdd(&cnt_s, 1); if (qq < CAP2) ckey[qq] = (klo << 16) | (unsigned)(32767 - bidx); }
      if (khi >= t0) { const int qq = atomicAdd(&cnt_s, 1); if (qq < CAP2) ckey[qq] = (khi << 16) | (unsigned)(32767 - (bidx + 1)); }
    }
    __syncthreads();
    cnt = cnt_s;
    __syncthreads();
    if ((cnt >= TOPK && cnt <= CAP2) || att == 17) break;
    if (cnt > CAP2) { tlo = t0; t0 = t0 + ((thi - t0 + 1) >> 1); }
    else { thi = t0; t0 = tlo + ((t0 - tlo) >> 1); }
    if (tid == 0) cnt_s = 0;
    __syncthreads();
  }
  const int n = min(cnt, CAP2);

  if (tid < 64) {
    unsigned lo = t0, hi = M;
    while (lo < hi) {
      const unsigned mid = (lo + hi + 1) >> 1;
      int c = 0;
      for (int i = lane; i < n; i += 64) c += (int)((ckey[i] >> 16) >= mid);
#pragma unroll
      for (int off = 32; off; off >>= 1) c += __shfl_xor(c, off, 64);
      if (c >= TOPK) lo = mid; else hi = mid - 1;
    }
    const unsigned t32 = lo;
    int c32 = 0;
    for (int i = lane; i < n; i += 64) c32 += (int)((ckey[i] >> 16) >= t32);
#pragma unroll
    for (int off = 32; off; off >>= 1) c32 += __shfl_xor(c32, off, 64);

    if (c32 <= 64) {
      cand64[lane] = 0;
      int base = 0;
      for (int r0c = 0; r0c < n; r0c += 64) {
        const int i = r0c + lane;
        const unsigned k = (i < n) ? ckey[i] : 0u;
        const bool p = (k >> 16) >= t32;
        const unsigned long long bm = __ballot(p);
        if (p) {
          const int ps = base + __popcll(bm & ((1ull << lane) - 1ull));
          if (ps < 64) cand64[ps] = k;
        }
        base += __popcll(bm);
      }
      unsigned v = cand64[lane];
#pragma unroll
      for (int k2 = 2; k2 <= 64; k2 <<= 1) {
#pragma unroll
        for (int j = k2 >> 1; j > 0; j >>= 1) {
          const unsigned o = __shfl_xor(v, j, 64);
          const bool lower = (lane & j) == 0;
          const bool descB = (lane & k2) == 0;
          const unsigned mxv = v > o ? v : o;
          const unsigned mnv = v > o ? o : v;
          v = (lower == descB) ? mxv : mnv;
        }
      }
      if (lane < TOPK) {
        okey[lane] = v >> 16;
        oidx[lane] = 32767 - (int)(v & 0x7FFFu);
      }
    } else {
      for (int k = 0; k < TOPK; ++k) {
        unsigned bk = 0;
        for (int j = lane; j < n; j += 64) bk = max(bk, ckey[j]);
#pragma unroll
        for (int off = 32; off; off >>= 1) bk = max(bk, __shfl_xor(bk, off, 64));
        if (lane == 0) {
          okey[k] = bk >> 16;
          oidx[k] = 32767 - (int)(bk & 0x7FFFu);
        }
        for (int j = lane; j < n; j += 64)
          if (ckey[j] == bk) ckey[j] = 0;
      }
    }
  }
  __syncthreads();

  if (tid < TOPK) {
    const float T = fabsf(temp[0]);
    const unsigned k0 = okey[tid];
    const unsigned u0 = (k0 & 0x8000u) ? (k0 ^ 0x8000u) : (k0 ^ 0xFFFFu);
    const unsigned km = okey[0];
    const unsigned um = (km & 0x8000u) ? (km ^ 0x8000u) : (km ^ 0xFFFFu);
    const float s = __uint_as_float(u0 << 16) * T;
    const float mx = __uint_as_float(um << 16) * T;
    const float e = __expf(s - mx);
    float sum = e;
#pragma unroll
    for (int off = 16; off; off >>= 1) sum += __shfl_xor(sum, off, 32);
    attn[(size_t)grow * TOPK + tid] = e / sum;
    idx_out[(size_t)grow * TOPK + tid] = oidx[tid];
  }
}

// ---------- fp8-V gather + residual + LayerNorm, 2 rows/block (unchanged) ----------
__global__ __launch_bounds__(256) void gather_ln_f8(const uchar* __restrict__ V8,
                                                    const float* __restrict__ Q,
                                                    const float* __restrict__ gamma,
                                                    const float* __restrict__ beta,
                                                    const float* __restrict__ attn,
                                                    const int* __restrict__ idx,
                                                    float* __restrict__ out) {
  const int tid = threadIdx.x;
  const int rh = tid >> 7;
  const int t7 = tid & 127;
  const int row = blockIdx.x * 2 + rh;
  __shared__ float a_s[2][TOPK];
  __shared__ int i_s[2][TOPK];
  __shared__ float redS[2][2], redQ[2][2];
  if (t7 < TOPK) {
    a_s[rh][t7] = attn[(size_t)row * TOPK + t7];
    i_s[rh][t7] = idx[(size_t)row * TOPK + t7];
  }
  __syncthreads();

  const int e0 = t7 * 8;
  float acc[8];
#pragma unroll
  for (int u = 0; u < 8; ++u) acc[u] = 0.f;
#pragma unroll
  for (int kb = 0; kb < TOPK; kb += 8) {
    uint2 v[8];
#pragma unroll
    for (int u = 0; u < 8; ++u)
      v[u] = *(const uint2*)&V8[(size_t)i_s[rh][kb + u] * D + e0];
#pragma unroll
    for (int u = 0; u < 8; ++u) {
      const float a = a_s[rh][kb + u];
      acc[0] = fmaf(a, __builtin_amdgcn_cvt_f32_fp8((int)v[u].x, 0), acc[0]);
      acc[1] = fmaf(a, __builtin_amdgcn_cvt_f32_fp8((int)v[u].x, 1), acc[1]);
      acc[2] = fmaf(a, __builtin_amdgcn_cvt_f32_fp8((int)v[u].x, 2), acc[2]);
      acc[3] = fmaf(a, __builtin_amdgcn_cvt_f32_fp8((int)v[u].x, 3), acc[3]);
      acc[4] = fmaf(a, __builtin_amdgcn_cvt_f32_fp8((int)v[u].y, 0), acc[4]);
      acc[5] = fmaf(a, __builtin_amdgcn_cvt_f32_fp8((int)v[u].y, 1), acc[5]);
      acc[6] = fmaf(a, __builtin_amdgcn_cvt_f32_fp8((int)v[u].y, 2), acc[6]);
      acc[7] = fmaf(a, __builtin_amdgcn_cvt_f32_fp8((int)v[u].y, 3), acc[7]);
    }
  }

  const float4 q0 = *(const float4*)&Q[(size_t)row * D + e0];
  const float4 q1 = *(const float4*)&Q[(size_t)row * D + e0 + 4];
  float x[8] = {acc[0] * INV_V8 + q0.x, acc[1] * INV_V8 + q0.y,
                acc[2] * INV_V8 + q0.z, acc[3] * INV_V8 + q0.w,
                acc[4] * INV_V8 + q1.x, acc[5] * INV_V8 + q1.y,
                acc[6] * INV_V8 + q1.z, acc[7] * INV_V8 + q1.w};
  float s = 0.f, ss = 0.f;
#pragma unroll
  for (int c = 0; c < 8; ++c) { s += x[c]; ss += x[c] * x[c]; }
#pragma unroll
  for (int off = 32; off; off >>= 1) {
    s += __shfl_xor(s, off, 64);
    ss += __shfl_xor(ss, off, 64);
  }
  const int w2 = (t7 >> 6);
  if ((tid & 63) == 0) { redS[rh][w2] = s; redQ[rh][w2] = ss; }
  __syncthreads();
  const float S = redS[rh][0] + redS[rh][1];
  const float SS = redQ[rh][0] + redQ[rh][1];
  const float mu = S * (1.0f / D);
  const float var = SS * (1.0f / D) - mu * mu;
  const float rstd = rsqrtf(var + 1e-5f);
  const float4 g0 = *(const float4*)&gamma[e0];
  const float4 g1 = *(const float4*)&gamma[e0 + 4];
  const float4 b0 = *(const float4*)&beta[e0];
  const float4 b1 = *(const float4*)&beta[e0 + 4];
  const float g[8] = {g0.x, g0.y, g0.z, g0.w, g1.x, g1.y, g1.z, g1.w};
  const float b[8] = {b0.x, b0.y, b0.z, b0.w, b1.x, b1.y, b1.z, b1.w};
  float4 o0, o1;
  o0.x = (x[0] - mu) * rstd * g[0] + b[0];
  o0.y = (x[1] - mu) * rstd * g[1] + b[1];
  o0.z = (x[2] - mu) * rstd * g[2] + b[2];
  o0.w = (x[3] - mu) * rstd * g[3] + b[3];
  o1.x = (x[4] - mu) * rstd * g[4] + b[4];
  o1.y = (x[5] - mu) * rstd * g[5] + b[5];
  o1.z = (x[6] - mu) * rstd * g[6] + b[6];
  o1.w = (x[7] - mu) * rstd * g[7] + b[7];
  *(float4*)&out[(size_t)row * D + e0] = o0;
  *(float4*)&out[(size_t)row * D + e0 + 4] = o1;
}

// ---------- fp32 fallback gather ----------
__global__ __launch_bounds__(256) void gather_ln_k(const float* __restrict__ V,
                                                   const float* __restrict__ Q,
                                                   const float* __restrict__ gamma,
                                                   const float* __restrict__ beta,
                                                   const float* __restrict__ attn,
                                                   const int* __restrict__ idx,
                                                   float* __restrict__ out) {
  const int row = blockIdx.x, tid = threadIdx.x;
  __shared__ float a_s[TOPK];
  __shared__ int i_s[TOPK];
  __shared__ float redS[4], redQ[4];
  if (tid < TOPK) {
    a_s[tid] = attn[(size_t)row * TOPK + tid];
    i_s[tid] = idx[(size_t)row * TOPK + tid];
  }
  __syncthreads();
  float4 acc = {0.f, 0.f, 0.f, 0.f};
#pragma unroll
  for (int kb = 0; kb < TOPK; kb += 8) {
    float4 v[8];
#pragma unroll
    for (int u = 0; u < 8; ++u)
      v[u] = ((const float4*)(V + (size_t)i_s[kb + u] * D))[tid];
#pragma unroll
    for (int u = 0; u < 8; ++u) {
      const float a = a_s[kb + u];
      acc.x = fmaf(a, v[u].x, acc.x);
      acc.y = fmaf(a, v[u].y, acc.y);
      acc.z = fmaf(a, v[u].z, acc.z);
      acc.w = fmaf(a, v[u].w, acc.w);
    }
  }
  const float4 q = ((const float4*)(Q + (size_t)row * D))[tid];
  float4 x = {acc.x + q.x, acc.y + q.y, acc.z + q.z, acc.w + q.w};
  float s = x.x + x.y + x.z + x.w;
  float ss = x.x * x.x + x.y * x.y + x.z * x.z + x.w * x.w;
#pragma unroll
  for (int off = 32; off; off >>= 1) {
    s += __shfl_xor(s, off, 64);
    ss += __shfl_xor(ss, off, 64);
  }
  const int wid = tid >> 6, lane = tid & 63;
  if (lane == 0) { redS[wid] = s; redQ[wid] = ss; }
  __syncthreads();
  const float S = redS[0] + redS[1] + redS[2] + redS[3];
  const float SS = redQ[0] + redQ[1] + redQ[2] + redQ[3];
  const float mu = S * (1.0f / D);
  const float var = SS * (1.0f / D) - mu * mu;
  const float rstd = rsqrtf(var + 1e-5f);
  const float4 g = ((const float4*)gamma)[tid];
  const float4 b = ((const float4*)beta)[tid];
  float4 o;
  o.x = (x.x - mu) * rstd * g.x + b.x;
  o.y = (x.y - mu) * rstd * g.y + b.y;
  o.z = (x.z - mu) * rstd * g.z + b.z;
  o.w = (x.w - mu) * rstd * g.w + b.w;
  ((float4*)(out + (size_t)row * D))[tid] = o;
}

extern "C" void kernel_launch(void* const* d_in, const int* in_sizes, int n_in,
                              void* d_out, int out_size, void* d_ws, size_t ws_size,
                              hipStream_t stream) {
  const float* Q = (const float*)d_in[0];
  const float* K = (const float*)d_in[1];
  const float* V = (const float*)d_in[2];
  const float* T = (const float*)d_in[3];
  const float* G = (const float*)d_in[4];
  const float* Bt = (const float*)d_in[5];
  float* out = (float*)d_out;
  float* attn = out + (size_t)NQ * D;

  char* ws = (char*)d_ws;
  const size_t off_q8 = 0;
  const size_t off_k8 = off_q8 + (size_t)NQ * D;                      // 8 MB
  const size_t off_idx = off_k8 + (size_t)NM * D;                     // +32 MB
  const size_t off_tm = off_idx + (size_t)NQ * TOPK * sizeof(int);    // +1 MB
  const size_t off_v8 = off_tm + (size_t)NBXT * 2048 * 2;             // +1 MB
  const size_t v8_bytes = (size_t)NM * D;                             // 32 MB

  const bool use_v8 = ws_size >= off_v8 + v8_bytes + (size_t)256 * NM * 2;
  const size_t off_sc = use_v8 ? off_v8 + v8_bytes : off_v8;

  unsigned* q8 = (unsigned*)(ws + off_q8);
  unsigned* k8 = (unsigned*)(ws + off_k8);
  int* idx = (int*)(ws + off_idx);
  ushort* tm = (ushort*)(ws + off_tm);
  unsigned* v8 = (unsigned*)(ws + off_v8);
  ushort* scores = (ushort*)(ws + off_sc);

  const size_t avail = ws_size > off_sc ? ws_size - off_sc : 0;
  int slice = 2048;
  while (slice > 256 && (size_t)slice * NM * 2ull > avail) slice >>= 1;

  norm_cast8_k<<<NQ, 256, 0, stream>>>(Q, q8);
  norm_cast8_k<<<NM, 256, 0, stream>>>(K, k8);
  if (use_v8) cast_v8_k<<<NM, 256, 0, stream>>>(V, v8);

  const int nbx = NM / 128;
  for (int s0 = 0; s0 < NQ; s0 += slice) {
    const int nby = slice / 128;
    gemm128<<<nbx * nby, 256, 0, stream>>>((const uchar*)q8 + (size_t)s0 * D,
                                           (const uchar*)k8, scores, tm, nby, slice);
    topk_k<<<slice, 512, 0, stream>>>(scores, tm, slice, s0, T, attn, idx);
  }
  if (use_v8)
    gather_ln_f8<<<NQ / 2, 256, 0, stream>>>((const uchar*)v8, Q, G, Bt, attn, idx, out);
  else
    gather_ln_k<<<NQ, 256, 0, stream>>>(V, Q, G, Bt, attn, idx, out);
}

// Round 18
// 580.290 us; speedup vs baseline: 1.2915x; 1.0209x over previous
//
#include <hip/hip_runtime.h>
#include <hip/hip_bf16.h>

#define D 1024
#define NQ 8192
#define NM 32768
#define TOPK 32
#define NBXT 256  // 128-col tiles per row

typedef __attribute__((ext_vector_type(8))) __bf16 bf16x8;
typedef __attribute__((ext_vector_type(4))) float f32x4;
typedef __attribute__((ext_vector_type(4))) int i32x4;
typedef __attribute__((ext_vector_type(8))) int i32x8;

__device__ __forceinline__ void load_lds16(const void* g, void* l) {
  __builtin_amdgcn_global_load_lds(
      (const __attribute__((address_space(1))) void*)g,
      (__attribute__((address_space(3))) void*)l, 16, 0, 0);
}

__device__ __forceinline__ ushort f2bf(float f) {
  unsigned u = __float_as_uint(f);
  unsigned r = (u + 0x7FFFu + ((u >> 16) & 1u)) >> 16;
  return (ushort)r;
}
__device__ __forceinline__ unsigned key16(unsigned u) {
  return u ^ ((u & 0x8000u) ? 0xFFFFu : 0x8000u);
}

#define FP8_SCALE 32.0f
#define INV_ACC (1.0f / 1024.0f)  // (1/FP8_SCALE)^2
#define V8_SCALE 16.0f
#define INV_V8 (1.0f / 16.0f)
#define SCALE_ONE 0x7F7F7F7F      // e8m0 1.0 in all 4 bytes

// ---------- row L2-normalize f32 -> fp8 e4m3 (x32), granule-permuted ----------
// Within each 128B k-block, 16B granule g stored at chunk p(g)=(g>>1)+(g&1)*4:
// a lane's k-range [l4*32, l4*32+32) = physical chunks l4 (lo) and l4+4 (hi)
// -> frag reads reproduce R16's measured-zero bank pattern (l4^x, (l4+4)^x).
__global__ __launch_bounds__(256) void norm_cast8_k(const float* __restrict__ in,
                                                    unsigned* __restrict__ out8) {
  const int row = blockIdx.x;
  const int tid = threadIdx.x;
  const float4 v = ((const float4*)(in + (size_t)row * D))[tid];
  float ss = v.x * v.x + v.y * v.y + v.z * v.z + v.w * v.w;
#pragma unroll
  for (int off = 32; off; off >>= 1) ss += __shfl_xor(ss, off, 64);
  __shared__ float wsum[4];
  const int wid = tid >> 6, lane = tid & 63;
  if (lane == 0) wsum[wid] = ss;
  __syncthreads();
  const float tot = wsum[0] + wsum[1] + wsum[2] + wsum[3];
  const float inv = FP8_SCALE / fmaxf(sqrtf(tot), 1e-12f);
  int r = __builtin_amdgcn_cvt_pk_fp8_f32(v.x * inv, v.y * inv, 0, false);
  r = __builtin_amdgcn_cvt_pk_fp8_f32(v.z * inv, v.w * inv, r, true);
  const int b = tid >> 5;         // 128B k-block
  const int g = (tid >> 2) & 7;   // granule within block
  const int w = tid & 3;          // word within granule
  const int p = (g >> 1) + (g & 1) * 4;
  out8[(size_t)row * 256 + b * 32 + p * 4 + w] = (unsigned)r;
}

// ---------- plain f32 -> fp8 e4m3 cast (V table, x16, linear layout) ----------
__global__ __launch_bounds__(256) void cast_v8_k(const float* __restrict__ in,
                                                 unsigned* __restrict__ out8) {
  const int row = blockIdx.x;
  const int tid = threadIdx.x;
  const float4 v = ((const float4*)(in + (size_t)row * D))[tid];
  int r = __builtin_amdgcn_cvt_pk_fp8_f32(v.x * V8_SCALE, v.y * V8_SCALE, 0, false);
  r = __builtin_amdgcn_cvt_pk_fp8_f32(v.z * V8_SCALE, v.w * V8_SCALE, r, true);
  out8[(size_t)row * 256 + tid] = (unsigned)r;
}

// ---------- 128x128 fp8 GEMM, BK=128, MX-scaled K=128 MFMA (scale=1.0) ----------
// R16 staging + R16's measured-zero frag-read chunk pattern; 16 scaled MFMA/tile.
__global__ __launch_bounds__(256, 4) void gemm128(const uchar* __restrict__ A8,
                                                  const uchar* __restrict__ B8,
                                                  ushort* __restrict__ C,
                                                  ushort* __restrict__ TM,
                                                  int nby, int srows) {
  __shared__ alignas(16) ushort lds[16384];  // 32KB: As 16KB | Bs 16KB; C-stage aliases
  __shared__ float wmax[2][128];
  uchar* const As = (uchar*)lds;
  uchar* const Bs = (uchar*)lds + 16384;
  const int tid = threadIdx.x;
  const int lane = tid & 63, wid = tid >> 6;
  const int l15 = lane & 15, l4 = lane >> 4;

  // T1: bijective XCD swizzle
  const int nwg = (int)gridDim.x;
  const int q = nwg >> 3, r = nwg & 7;
  const int xcd = (int)blockIdx.x & 7, pos = (int)blockIdx.x >> 3;
  const int wg = (xcd < r ? xcd * (q + 1) : r * (q + 1) + (xcd - r) * q) + pos;
  const int bx = wg / nby, by = wg % nby;

  const int wr = wid >> 1, wc = wid & 1;  // 2x2 waves, each 64x64 of C

  f32x4 acc[4][4];
#pragma unroll
  for (int m = 0; m < 4; m++)
#pragma unroll
    for (int n = 0; n < 4; n++) acc[m][n] = f32x4{0.f, 0.f, 0.f, 0.f};

  // staging (R13/R16 verbatim): 1024 chunks(16B)/operand/tile; thread t, load l:
  // chunk ci = l*256 + t -> row = l*32 + (t>>3); stored slot t&7 holds logical
  // chunk (t&7)^(row&7) (pre-swizzled source, linear LDS dest).
  const int srow = tid >> 3;
  const int cc = ((tid & 7) ^ ((tid >> 3) & 7)) << 4;
  const uchar* gA = A8 + ((size_t)by * 128 + srow) * 1024 + cc;
  const uchar* gB = B8 + ((size_t)bx * 128 + srow) * 1024 + cc;
  uchar* const ldsA = As + wid * 1024;
  uchar* const ldsB = Bs + wid * 1024;

  // frag reads (R16 pattern, measured zero conflicts): physical chunk l4 (lo)
  // and l4+4 (hi), stored at ^(l15&7).
  const int ob0 = (((0 + l4) ^ (l15 & 7)) << 4);
  const int ob1 = (((4 + l4) ^ (l15 & 7)) << 4);
  const uchar* const abase = As + (wr * 64 + l15) * 128;
  const uchar* const bbase = Bs + (wc * 64 + l15) * 128;

#pragma unroll 1
  for (int kt = 0; kt < 8; ++kt) {
    const int ko = kt * 128;
#pragma unroll
    for (int l = 0; l < 4; ++l) {
      load_lds16(gA + (size_t)l * 32 * 1024 + ko, ldsA + l * 4096);
      load_lds16(gB + (size_t)l * 32 * 1024 + ko, ldsB + l * 4096);
    }
    __syncthreads();
    i32x8 af[4], bfv[4];
#pragma unroll
    for (int m = 0; m < 4; ++m) {
      const i32x4 lo = *(const i32x4*)(abase + m * 2048 + ob0);
      const i32x4 hi = *(const i32x4*)(abase + m * 2048 + ob1);
      af[m] = (i32x8){lo[0], lo[1], lo[2], lo[3], hi[0], hi[1], hi[2], hi[3]};
    }
#pragma unroll
    for (int n = 0; n < 4; ++n) {
      const i32x4 lo = *(const i32x4*)(bbase + n * 2048 + ob0);
      const i32x4 hi = *(const i32x4*)(bbase + n * 2048 + ob1);
      bfv[n] = (i32x8){lo[0], lo[1], lo[2], lo[3], hi[0], hi[1], hi[2], hi[3]};
    }
#pragma unroll
    for (int m = 0; m < 4; ++m)
#pragma unroll
      for (int n = 0; n < 4; ++n)
        acc[m][n] = __builtin_amdgcn_mfma_scale_f32_16x16x128_f8f6f4(
            af[m], bfv[n], acc[m][n], 0, 0, 0, SCALE_ONE, 0, SCALE_ONE);
    __syncthreads();
  }

  // epilogue 1: per-row max over this block's 128 cols (atomic-free); scale acc
#pragma unroll
  for (int m = 0; m < 4; ++m)
#pragma unroll
    for (int j = 0; j < 4; ++j) {
      float fm = fmaxf(fmaxf(acc[m][0][j], acc[m][1][j]), fmaxf(acc[m][2][j], acc[m][3][j]));
#pragma unroll
      for (int off = 1; off < 16; off <<= 1) fm = fmaxf(fm, __shfl_xor(fm, off, 64));
      if (l15 == 0) wmax[wc][wr * 64 + l4 * 4 + m * 16 + j] = fm;
    }
  __syncthreads();
  if (tid < 128) {
    const float fm = fmaxf(wmax[0][tid], wmax[1][tid]) * INV_ACC;
    TM[(size_t)bx * srows + by * 128 + tid] = (ushort)key16((unsigned)f2bf(fm));
  }

  // epilogue 2: stage C-tile to LDS (chunk-XOR swizzle), stream out coalesced.
#pragma unroll
  for (int m = 0; m < 4; ++m)
#pragma unroll
    for (int n = 0; n < 4; ++n) {
      const int col = wc * 64 + n * 16 + l15;
      const int c8 = col >> 3, c7 = col & 7;
#pragma unroll
      for (int j = 0; j < 4; ++j) {
        const int row = wr * 64 + m * 16 + l4 * 4 + j;
        lds[row * 128 + ((c8 ^ (row & 7)) << 3) + c7] = f2bf(acc[m][n][j] * INV_ACC);
      }
    }
  __syncthreads();
  const int orow = tid >> 4, seg = tid & 15;
#pragma unroll
  for (int p = 0; p < 8; ++p) {
    const int row = p * 16 + orow;
    const bf16x8 v = *(const bf16x8*)&lds[row * 128 + ((seg ^ (row & 7)) << 3)];
    *(bf16x8*)&C[((size_t)by * 128 + row) * NM + bx * 128 + seg * 8] = v;
  }
}

// ---------- top-32 with 128-col tile-max prefilter (unchanged) ----------
#define CAP2 1024
__global__ __launch_bounds__(512) void topk_k(const ushort* __restrict__ scores,
                                              const ushort* __restrict__ tmax,
                                              int srows, int row_base,
                                              const float* __restrict__ temp,
                                              float* __restrict__ attn,
                                              int* __restrict__ idx_out) {
  const int lrow = blockIdx.x;
  const int grow = row_base + lrow;
  const int tid = threadIdx.x;
  const int lane = tid & 63, wid = tid >> 6;
  __shared__ unsigned tlb_s, M_s;
  __shared__ int nqt_s, cnt_s;
  __shared__ ushort qt[NBXT];
  __shared__ unsigned ckey[CAP2];
  __shared__ unsigned cand64[64];
  __shared__ unsigned okey[TOPK];
  __shared__ int oidx[TOPK];

  if (tid == 0) cnt_s = 0;

  if (tid < 64) {
    const unsigned k0 = tmax[(size_t)lane * srows + lrow];
    const unsigned k1 = tmax[(size_t)(lane + 64) * srows + lrow];
    const unsigned k2 = tmax[(size_t)(lane + 128) * srows + lrow];
    const unsigned k3 = tmax[(size_t)(lane + 192) * srows + lrow];
    unsigned mx = max(max(k0, k1), max(k2, k3));
#pragma unroll
    for (int off = 32; off; off >>= 1) mx = max(mx, __shfl_xor(mx, off, 64));
    unsigned lo = 0, hi = mx;
    while (lo < hi) {
      const unsigned mid = (lo + hi + 1) >> 1;
      int c = (int)(k0 >= mid) + (int)(k1 >= mid) + (int)(k2 >= mid) + (int)(k3 >= mid);
#pragma unroll
      for (int off = 32; off; off >>= 1) c += __shfl_xor(c, off, 64);
      if (c >= TOPK) lo = mid; else hi = mid - 1;
    }
    int base = 0;
    {
      const bool p = k0 >= lo;
      const unsigned long long bm = __ballot(p);
      if (p) qt[base + __popcll(bm & ((1ull << lane) - 1ull))] = (ushort)lane;
      base += __popcll(bm);
    }
    {
      const bool p = k1 >= lo;
      const unsigned long long bm = __ballot(p);
      if (p) qt[base + __popcll(bm & ((1ull << lane) - 1ull))] = (ushort)(lane + 64);
      base += __popcll(bm);
    }
    {
      const bool p = k2 >= lo;
      const unsigned long long bm = __ballot(p);
      if (p) qt[base + __popcll(bm & ((1ull << lane) - 1ull))] = (ushort)(lane + 128);
      base += __popcll(bm);
    }
    {
      const bool p = k3 >= lo;
      const unsigned long long bm = __ballot(p);
      if (p) qt[base + __popcll(bm & ((1ull << lane) - 1ull))] = (ushort)(lane + 192);
      base += __popcll(bm);
    }
    if (lane == 0) { nqt_s = base; tlb_s = lo; M_s = mx; }
  }
  __syncthreads();
  const unsigned M = M_s;
  const int nqt = nqt_s;
  unsigned t0 = tlb_s;
  unsigned tlo = t0, thi = M;

  const unsigned* rowu = (const unsigned*)(scores + (size_t)lrow * NM);
  int cnt = 0;
  for (int att = 0; att < 18; ++att) {
    for (int i = wid; i < nqt; i += 8) {
      const int tb = qt[i];
      const unsigned u = rowu[tb * 64 + lane];
      const unsigned m = (u >> 15) & 0x00010001u;
      const unsigned kk = u ^ (m * 0x7FFFu + 0x80008000u);
      const unsigned klo = kk & 0xFFFFu, khi = kk >> 16;
      const int bidx = tb * 128 + lane * 2;
      if (klo >= t0) { const int qq = atomicAdd(&cnt_s, 1); if (qq < CAP2) ckey[qq] = (klo << 16) | (unsigned)(32767 - bidx); }
      if (khi >= t0) { const int qq = atomicAdd(&cnt_s, 1); if (qq < CAP2) ckey[qq] = (khi << 16) | (unsigned)(32767 - (bidx + 1)); }
    }
    __syncthreads();
    cnt = cnt_s;
    __syncthreads();
    if ((cnt >= TOPK && cnt <= CAP2) || att == 17) break;
    if (cnt > CAP2) { tlo = t0; t0 = t0 + ((thi - t0 + 1) >> 1); }
    else { thi = t0; t0 = tlo + ((t0 - tlo) >> 1); }
    if (tid == 0) cnt_s = 0;
    __syncthreads();
  }
  const int n = min(cnt, CAP2);

  if (tid < 64) {
    unsigned lo = t0, hi = M;
    while (lo < hi) {
      const unsigned mid = (lo + hi + 1) >> 1;
      int c = 0;
      for (int i = lane; i < n; i += 64) c += (int)((ckey[i] >> 16) >= mid);
#pragma unroll
      for (int off = 32; off; off >>= 1) c += __shfl_xor(c, off, 64);
      if (c >= TOPK) lo = mid; else hi = mid - 1;
    }
    const unsigned t32 = lo;
    int c32 = 0;
    for (int i = lane; i < n; i += 64) c32 += (int)((ckey[i] >> 16) >= t32);
#pragma unroll
    for (int off = 32; off; off >>= 1) c32 += __shfl_xor(c32, off, 64);

    if (c32 <= 64) {
      cand64[lane] = 0;
      int base = 0;
      for (int r0c = 0; r0c < n; r0c += 64) {
        const int i = r0c + lane;
        const unsigned k = (i < n) ? ckey[i] : 0u;
        const bool p = (k >> 16) >= t32;
        const unsigned long long bm = __ballot(p);
        if (p) {
          const int ps = base + __popcll(bm & ((1ull << lane) - 1ull));
          if (ps < 64) cand64[ps] = k;
        }
        base += __popcll(bm);
      }
      unsigned v = cand64[lane];
#pragma unroll
      for (int k2 = 2; k2 <= 64; k2 <<= 1) {
#pragma unroll
        for (int j = k2 >> 1; j > 0; j >>= 1) {
          const unsigned o = __shfl_xor(v, j, 64);
          const bool lower = (lane & j) == 0;
          const bool descB = (lane & k2) == 0;
          const unsigned mxv = v > o ? v : o;
          const unsigned mnv = v > o ? o : v;
          v = (lower == descB) ? mxv : mnv;
        }
      }
      if (lane < TOPK) {
        okey[lane] = v >> 16;
        oidx[lane] = 32767 - (int)(v & 0x7FFFu);
      }
    } else {
      for (int k = 0; k < TOPK; ++k) {
        unsigned bk = 0;
        for (int j = lane; j < n; j += 64) bk = max(bk, ckey[j]);
#pragma unroll
        for (int off = 32; off; off >>= 1) bk = max(bk, __shfl_xor(bk, off, 64));
        if (lane == 0) {
          okey[k] = bk >> 16;
          oidx[k] = 32767 - (int)(bk & 0x7FFFu);
        }
        for (int j = lane; j < n; j += 64)
          if (ckey[j] == bk) ckey[j] = 0;
      }
    }
  }
  __syncthreads();

  if (tid < TOPK) {
    const float T = fabsf(temp[0]);
    const unsigned k0 = okey[tid];
    const unsigned u0 = (k0 & 0x8000u) ? (k0 ^ 0x8000u) : (k0 ^ 0xFFFFu);
    const unsigned km = okey[0];
    const unsigned um = (km & 0x8000u) ? (km ^ 0x8000u) : (km ^ 0xFFFFu);
    const float s = __uint_as_float(u0 << 16) * T;
    const float mx = __uint_as_float(um << 16) * T;
    const float e = __expf(s - mx);
    float sum = e;
#pragma unroll
    for (int off = 16; off; off >>= 1) sum += __shfl_xor(sum, off, 32);
    attn[(size_t)grow * TOPK + tid] = e / sum;
    idx_out[(size_t)grow * TOPK + tid] = oidx[tid];
  }
}

// ---------- fp8-V gather + residual + LayerNorm, 2 rows/block (unchanged) ----------
__global__ __launch_bounds__(256) void gather_ln_f8(const uchar* __restrict__ V8,
                                                    const float* __restrict__ Q,
                                                    const float* __restrict__ gamma,
                                                    const float* __restrict__ beta,
                                                    const float* __restrict__ attn,
                                                    const int* __restrict__ idx,
                                                    float* __restrict__ out) {
  const int tid = threadIdx.x;
  const int rh = tid >> 7;
  const int t7 = tid & 127;
  const int row = blockIdx.x * 2 + rh;
  __shared__ float a_s[2][TOPK];
  __shared__ int i_s[2][TOPK];
  __shared__ float redS[2][2], redQ[2][2];
  if (t7 < TOPK) {
    a_s[rh][t7] = attn[(size_t)row * TOPK + t7];
    i_s[rh][t7] = idx[(size_t)row * TOPK + t7];
  }
  __syncthreads();

  const int e0 = t7 * 8;
  float acc[8];
#pragma unroll
  for (int u = 0; u < 8; ++u) acc[u] = 0.f;
#pragma unroll
  for (int kb = 0; kb < TOPK; kb += 8) {
    uint2 v[8];
#pragma unroll
    for (int u = 0; u < 8; ++u)
      v[u] = *(const uint2*)&V8[(size_t)i_s[rh][kb + u] * D + e0];
#pragma unroll
    for (int u = 0; u < 8; ++u) {
      const float a = a_s[rh][kb + u];
      acc[0] = fmaf(a, __builtin_amdgcn_cvt_f32_fp8((int)v[u].x, 0), acc[0]);
      acc[1] = fmaf(a, __builtin_amdgcn_cvt_f32_fp8((int)v[u].x, 1), acc[1]);
      acc[2] = fmaf(a, __builtin_amdgcn_cvt_f32_fp8((int)v[u].x, 2), acc[2]);
      acc[3] = fmaf(a, __builtin_amdgcn_cvt_f32_fp8((int)v[u].x, 3), acc[3]);
      acc[4] = fmaf(a, __builtin_amdgcn_cvt_f32_fp8((int)v[u].y, 0), acc[4]);
      acc[5] = fmaf(a, __builtin_amdgcn_cvt_f32_fp8((int)v[u].y, 1), acc[5]);
      acc[6] = fmaf(a, __builtin_amdgcn_cvt_f32_fp8((int)v[u].y, 2), acc[6]);
      acc[7] = fmaf(a, __builtin_amdgcn_cvt_f32_fp8((int)v[u].y, 3), acc[7]);
    }
  }

  const float4 q0 = *(const float4*)&Q[(size_t)row * D + e0];
  const float4 q1 = *(const float4*)&Q[(size_t)row * D + e0 + 4];
  float x[8] = {acc[0] * INV_V8 + q0.x, acc[1] * INV_V8 + q0.y,
                acc[2] * INV_V8 + q0.z, acc[3] * INV_V8 + q0.w,
                acc[4] * INV_V8 + q1.x, acc[5] * INV_V8 + q1.y,
                acc[6] * INV_V8 + q1.z, acc[7] * INV_V8 + q1.w};
  float s = 0.f, ss = 0.f;
#pragma unroll
  for (int c = 0; c < 8; ++c) { s += x[c]; ss += x[c] * x[c]; }
#pragma unroll
  for (int off = 32; off; off >>= 1) {
    s += __shfl_xor(s, off, 64);
    ss += __shfl_xor(ss, off, 64);
  }
  const int w2 = (t7 >> 6);
  if ((tid & 63) == 0) { redS[rh][w2] = s; redQ[rh][w2] = ss; }
  __syncthreads();
  const float S = redS[rh][0] + redS[rh][1];
  const float SS = redQ[rh][0] + redQ[rh][1];
  const float mu = S * (1.0f / D);
  const float var = SS * (1.0f / D) - mu * mu;
  const float rstd = rsqrtf(var + 1e-5f);
  const float4 g0 = *(const float4*)&gamma[e0];
  const float4 g1 = *(const float4*)&gamma[e0 + 4];
  const float4 b0 = *(const float4*)&beta[e0];
  const float4 b1 = *(const float4*)&beta[e0 + 4];
  const float g[8] = {g0.x, g0.y, g0.z, g0.w, g1.x, g1.y, g1.z, g1.w};
  const float b[8] = {b0.x, b0.y, b0.z, b0.w, b1.x, b1.y, b1.z, b1.w};
  float4 o0, o1;
  o0.x = (x[0] - mu) * rstd * g[0] + b[0];
  o0.y = (x[1] - mu) * rstd * g[1] + b[1];
  o0.z = (x[2] - mu) * rstd * g[2] + b[2];
  o0.w = (x[3] - mu) * rstd * g[3] + b[3];
  o1.x = (x[4] - mu) * rstd * g[4] + b[4];
  o1.y = (x[5] - mu) * rstd * g[5] + b[5];
  o1.z = (x[6] - mu) * rstd * g[6] + b[6];
  o1.w = (x[7] - mu) * rstd * g[7] + b[7];
  *(float4*)&out[(size_t)row * D + e0] = o0;
  *(float4*)&out[(size_t)row * D + e0 + 4] = o1;
}

// ---------- fp32 fallback gather ----------
__global__ __launch_bounds__(256) void gather_ln_k(const float* __restrict__ V,
                                                   const float* __restrict__ Q,
                                                   const float* __restrict__ gamma,
                                                   const float* __restrict__ beta,
                                                   const float* __restrict__ attn,
                                                   const int* __restrict__ idx,
                                                   float* __restrict__ out) {
  const int row = blockIdx.x, tid = threadIdx.x;
  __shared__ float a_s[TOPK];
  __shared__ int i_s[TOPK];
  __shared__ float redS[4], redQ[4];
  if (tid < TOPK) {
    a_s[tid] = attn[(size_t)row * TOPK + tid];
    i_s[tid] = idx[(size_t)row * TOPK + tid];
  }
  __syncthreads();
  float4 acc = {0.f, 0.f, 0.f, 0.f};
#pragma unroll
  for (int kb = 0; kb < TOPK; kb += 8) {
    float4 v[8];
#pragma unroll
    for (int u = 0; u < 8; ++u)
      v[u] = ((const float4*)(V + (size_t)i_s[kb + u] * D))[tid];
#pragma unroll
    for (int u = 0; u < 8; ++u) {
      const float a = a_s[kb + u];
      acc.x = fmaf(a, v[u].x, acc.x);
      acc.y = fmaf(a, v[u].y, acc.y);
      acc.z = fmaf(a, v[u].z, acc.z);
      acc.w = fmaf(a, v[u].w, acc.w);
    }
  }
  const float4 q = ((const float4*)(Q + (size_t)row * D))[tid];
  float4 x = {acc.x + q.x, acc.y + q.y, acc.z + q.z, acc.w + q.w};
  float s = x.x + x.y + x.z + x.w;
  float ss = x.x * x.x + x.y * x.y + x.z * x.z + x.w * x.w;
#pragma unroll
  for (int off = 32; off; off >>= 1) {
    s += __shfl_xor(s, off, 64);
    ss += __shfl_xor(ss, off, 64);
  }
  const int wid = tid >> 6, lane = tid & 63;
  if (lane == 0) { redS[wid] = s; redQ[wid] = ss; }
  __syncthreads();
  const float S = redS[0] + redS[1] + redS[2] + redS[3];
  const float SS = redQ[0] + redQ[1] + redQ[2] + redQ[3];
  const float mu = S * (1.0f / D);
  const float var = SS * (1.0f / D) - mu * mu;
  const float rstd = rsqrtf(var + 1e-5f);
  const float4 g = ((const float4*)gamma)[tid];
  const float4 b = ((const float4*)beta)[tid];
  float4 o;
  o.x = (x.x - mu) * rstd * g.x + b.x;
  o.y = (x.y - mu) * rstd * g.y + b.y;
  o.z = (x.z - mu) * rstd * g.z + b.z;
  o.w = (x.w - mu) * rstd * g.w + b.w;
  ((float4*)(out + (size_t)row * D))[tid] = o;
}

extern "C" void kernel_launch(void* const* d_in, const int* in_sizes, int n_in,
                              void* d_out, int out_size, void* d_ws, size_t ws_size,
                              hipStream_t stream) {
  const float* Q = (const float*)d_in[0];
  const float* K = (const float*)d_in[1];
  const float* V = (const float*)d_in[2];
  const float* T = (const float*)d_in[3];
  const float* G = (const float*)d_in[4];
  const float* Bt = (const float*)d_in[5];
  float* out = (float*)d_out;
  float* attn = out + (size_t)NQ * D;

  char* ws = (char*)d_ws;
  const size_t off_q8 = 0;
  const size_t off_k8 = off_q8 + (size_t)NQ * D;                      // 8 MB
  const size_t off_idx = off_k8 + (size_t)NM * D;                     // +32 MB
  const size_t off_tm = off_idx + (size_t)NQ * TOPK * sizeof(int);    // +1 MB
  const size_t off_v8 = off_tm + (size_t)NBXT * 2048 * 2;             // +1 MB
  const size_t v8_bytes = (size_t)NM * D;                             // 32 MB

  const bool use_v8 = ws_size >= off_v8 + v8_bytes + (size_t)256 * NM * 2;
  const size_t off_sc = use_v8 ? off_v8 + v8_bytes : off_v8;

  unsigned* q8 = (unsigned*)(ws + off_q8);
  unsigned* k8 = (unsigned*)(ws + off_k8);
  int* idx = (int*)(ws + off_idx);
  ushort* tm = (ushort*)(ws + off_tm);
  unsigned* v8 = (unsigned*)(ws + off_v8);
  ushort* scores = (ushort*)(ws + off_sc);

  const size_t avail = ws_size > off_sc ? ws_size - off_sc : 0;
  int slice = 2048;
  while (slice > 256 && (size_t)slice * NM * 2ull > avail) slice >>= 1;

  norm_cast8_k<<<NQ, 256, 0, stream>>>(Q, q8);
  norm_cast8_k<<<NM, 256, 0, stream>>>(K, k8);
  if (use_v8) cast_v8_k<<<NM, 256, 0, stream>>>(V, v8);

  const int nbx = NM / 128;
  for (int s0 = 0; s0 < NQ; s0 += slice) {
    const int nby = slice / 128;
    gemm128<<<nbx * nby, 256, 0, stream>>>((const uchar*)q8 + (size_t)s0 * D,
                                           (const uchar*)k8, scores, tm, nby, slice);
    topk_k<<<slice, 512, 0, stream>>>(scores, tm, slice, s0, T, attn, idx);
  }
  if (use_v8)
    gather_ln_f8<<<NQ / 2, 256, 0, stream>>>((const uchar*)v8, Q, G, Bt, attn, idx, out);
  else
    gather_ln_k<<<NQ, 256, 0, stream>>>(V, Q, G, Bt, attn, idx, out);
}